// Round 1
// baseline (1081.135 us; speedup 1.0000x reference)
//
#include <hip/hip_runtime.h>

#define NEG_SLOPE 0.2f

__device__ inline float readlane_f(float v, int l) {
    return __int_as_float(__builtin_amdgcn_readlane(__float_as_int(v), l));
}
__device__ inline int readlane_i(int v, int l) {
    return __builtin_amdgcn_readlane(v, l);
}

// ---------------- CSR build ----------------

__global__ void hist_kernel(const int* __restrict__ dst, int e, int* __restrict__ counts) {
    int stride = gridDim.x * blockDim.x;
    for (int i = blockIdx.x * blockDim.x + threadIdx.x; i < e; i += stride)
        atomicAdd(&counts[dst[i]], 1);
}

// counts -> exclusive scan. Writes row_off[0..n] and rewrites counts[] as the
// scatter cursor (== exclusive offsets). Single block of 1024 threads.
__global__ void scan_kernel(int* __restrict__ counts, int* __restrict__ row_off, int n) {
    __shared__ int part[1024];
    int tid = threadIdx.x;
    int per = (n + 1023) / 1024;
    int start = tid * per;
    int end = min(start + per, n);
    int s = 0;
    for (int i = start; i < end; ++i) s += counts[i];
    part[tid] = s;
    __syncthreads();
    for (int off = 1; off < 1024; off <<= 1) {
        int v = part[tid];
        int o = (tid >= off) ? part[tid - off] : 0;
        __syncthreads();
        part[tid] = v + o;
        __syncthreads();
    }
    int run = (tid == 0) ? 0 : part[tid - 1];
    for (int i = start; i < end; ++i) {
        int c = counts[i];
        row_off[i] = run;
        counts[i] = run;   // cursor for scatter
        run += c;
    }
    if (start < n && end == n) row_off[n] = run;
}

__global__ void scatter_kernel(const int* __restrict__ src, const int* __restrict__ dst, int e,
                               int* __restrict__ cursor, int* __restrict__ csr_src) {
    int stride = gridDim.x * blockDim.x;
    for (int i = blockIdx.x * blockDim.x + threadIdx.x; i < e; i += stride) {
        int pos = atomicAdd(&cursor[dst[i]], 1);
        csr_src[pos] = src[i];
    }
}

// ---------------- GEMM + attention dots ----------------
// h[v][j] = sum_k x[v][k] * W[k][j];  el[v] = h[v].attn_l;  er[v] = h[v].attn_r
// One wave per node; lane = output feature j (64 features == wave width).
template <int K>
__global__ void gemm_attn_kernel(const float* __restrict__ x, const float* __restrict__ W,
                                 const float* __restrict__ al, const float* __restrict__ ar,
                                 float* __restrict__ h, float* __restrict__ el,
                                 float* __restrict__ er, int n) {
    __shared__ float Wl[K * 64];
    for (int i = threadIdx.x; i < K * 64; i += blockDim.x) Wl[i] = W[i];
    __syncthreads();
    int lane = threadIdx.x & 63;
    int gwave = (blockIdx.x * blockDim.x + threadIdx.x) >> 6;
    int nwaves = (gridDim.x * blockDim.x) >> 6;
    float a_l = al[lane], a_r = ar[lane];
    for (int v = gwave; v < n; v += nwaves) {
        const float* xr = x + (size_t)v * K;
        float x0 = xr[lane];
        float x1 = (K > 64) ? xr[64 + lane] : 0.f;
        float acc = 0.f;
#pragma unroll
        for (int k = 0; k < 64; ++k)
            acc = fmaf(readlane_f(x0, k), Wl[k * 64 + lane], acc);
        if (K > 64) {
#pragma unroll
            for (int k = 0; k < 64; ++k)
                acc = fmaf(readlane_f(x1, k), Wl[(64 + k) * 64 + lane], acc);
        }
        h[(size_t)v * 64 + lane] = acc;
        float pl = acc * a_l, pr = acc * a_r;
#pragma unroll
        for (int off = 32; off > 0; off >>= 1) {
            pl += __shfl_down(pl, off);
            pr += __shfl_down(pr, off);
        }
        if (lane == 0) { el[v] = pl; er[v] = pr; }
    }
}

// ---------------- softmax-aggregate ----------------
// One wave per dst node v; lane = output feature. Single pass over incoming
// edges: acc[lane] += exp(e) * h[src][lane]; ssum += exp(e); out = acc/ssum + b.
// (No max-subtraction: |e| is bounded ~8 given input scales, exp() safe in fp32;
// the normalized ratio matches the reference to fp rounding.)
__global__ void agg_kernel(const int* __restrict__ row_off, const int* __restrict__ csr_src,
                           const float* __restrict__ h, const float* __restrict__ el,
                           const float* __restrict__ er, const float* __restrict__ bias,
                           float* __restrict__ out, int n, int do_relu) {
    int lane = threadIdx.x & 63;
    int gwave = (blockIdx.x * blockDim.x + threadIdx.x) >> 6;
    int nwaves = (gridDim.x * blockDim.x) >> 6;
    float b = bias[lane];
    for (int v = gwave; v < n; v += nwaves) {
        int rs = row_off[v], re = row_off[v + 1];
        float er_v = er[v];
        float acc = 0.f, ssum = 0.f;
        for (int base = rs; base < re; base += 64) {
            int cnt = min(64, re - base);
            int s_e = 0;
            float ex = 0.f;
            if (lane < cnt) {
                s_e = csr_src[base + lane];
                float ev = el[s_e] + er_v;
                ev = (ev >= 0.f) ? ev : NEG_SLOPE * ev;
                ex = __expf(ev);
            }
            // wave-reduce chunk sum of ex (all lanes get it)
            float cs = ex;
#pragma unroll
            for (int off = 32; off > 0; off >>= 1) cs += __shfl_xor(cs, off);
            ssum += cs;
            for (int j = 0; j < cnt; ++j) {
                int sj = readlane_i(s_e, j);
                float exj = readlane_f(ex, j);
                acc = fmaf(exj, h[(size_t)sj * 64 + lane], acc);
            }
        }
        float o = (re > rs) ? (acc / ssum + b) : b;
        if (do_relu) o = fmaxf(o, 0.f);
        out[(size_t)v * 64 + lane] = o;
    }
}

extern "C" void kernel_launch(void* const* d_in, const int* in_sizes, int n_in,
                              void* d_out, int out_size, void* d_ws, size_t ws_size,
                              hipStream_t stream) {
    (void)n_in; (void)out_size; (void)ws_size;
    const float* features = (const float*)d_in[0];
    // d_in[1] = edge_weights, unused by the reference forward
    const int*   src = (const int*)d_in[2];
    const int*   dst = (const int*)d_in[3];
    const float* W1  = (const float*)d_in[4];
    const float* al1 = (const float*)d_in[5];
    const float* ar1 = (const float*)d_in[6];
    const float* b1  = (const float*)d_in[7];
    const float* W2  = (const float*)d_in[8];
    const float* al2 = (const float*)d_in[9];
    const float* ar2 = (const float*)d_in[10];
    const float* b2  = (const float*)d_in[11];

    const int n = in_sizes[0] / 128;   // 100000
    const int e = in_sizes[2];         // 1600000
    float* out = (float*)d_out;

    // workspace carve-up (~59 MB)
    char* p = (char*)d_ws;
    auto alloc = [&](size_t bytes) -> char* {
        char* q = p;
        p += (bytes + 255) & ~(size_t)255;
        return q;
    };
    int*   cursor  = (int*)alloc((size_t)n * 4);          // counts -> cursor
    int*   row_off = (int*)alloc((size_t)(n + 1) * 4);
    int*   csr_src = (int*)alloc((size_t)e * 4);
    float* h       = (float*)alloc((size_t)n * 64 * 4);   // layer GEMM out (reused)
    float* hr      = (float*)alloc((size_t)n * 64 * 4);   // relu(agg1) = layer2 input
    float* el      = (float*)alloc((size_t)n * 4);
    float* er      = (float*)alloc((size_t)n * 4);

    // CSR by dst (shared by both layers)
    hipMemsetAsync(cursor, 0, (size_t)n * 4, stream);
    hist_kernel<<<2048, 256, 0, stream>>>(dst, e, cursor);
    scan_kernel<<<1, 1024, 0, stream>>>(cursor, row_off, n);
    scatter_kernel<<<2048, 256, 0, stream>>>(src, dst, e, cursor, csr_src);

    // layer 1
    gemm_attn_kernel<128><<<512, 256, 0, stream>>>(features, W1, al1, ar1, h, el, er, n);
    agg_kernel<<<1024, 256, 0, stream>>>(row_off, csr_src, h, el, er, b1, hr, n, 1);

    // layer 2
    gemm_attn_kernel<64><<<512, 256, 0, stream>>>(hr, W2, al2, ar2, h, el, er, n);
    agg_kernel<<<1024, 256, 0, stream>>>(row_off, csr_src, h, el, er, b2, out, n, 0);
}

// Round 2
// 966.711 us; speedup vs baseline: 1.1184x; 1.1184x over previous
//
#include <hip/hip_runtime.h>

#define NEG_SLOPE 0.2f

__device__ inline float readlane_f(float v, int l) {
    return __int_as_float(__builtin_amdgcn_readlane(__float_as_int(v), l));
}
__device__ inline int readlane_i(int v, int l) {
    return __builtin_amdgcn_readlane(v, l);
}

// ---------------- CSR build ----------------

__global__ void hist_kernel(const int* __restrict__ dst, int e, int* __restrict__ counts) {
    int stride = gridDim.x * blockDim.x;
    for (int i = blockIdx.x * blockDim.x + threadIdx.x; i < e; i += stride)
        atomicAdd(&counts[dst[i]], 1);
}

// Phase A: per-block partial sums of counts. 256 blocks x 256 threads.
__global__ void scan_block_sum(const int* __restrict__ counts, int* __restrict__ bsum,
                               int n, int chunk) {
    __shared__ int red[256];
    int b = blockIdx.x, t = threadIdx.x;
    int s = b * chunk, e = min(s + chunk, n);
    int acc = 0;
    for (int i = s + t; i < e; i += 256) acc += counts[i];
    red[t] = acc;
    __syncthreads();
    for (int o = 128; o > 0; o >>= 1) {
        if (t < o) red[t] += red[t + o];
        __syncthreads();
    }
    if (t == 0) bsum[b] = red[0];
}

// Phase B: exclusive scan of the 256 block sums (in place). 1 block x 256.
__global__ void scan_bsum(int* __restrict__ bsum, int nb) {
    __shared__ int tmp[256];
    int t = threadIdx.x;
    int v = (t < nb) ? bsum[t] : 0;
    tmp[t] = v;
    __syncthreads();
    for (int o = 1; o < 256; o <<= 1) {
        int x = tmp[t];
        int y = (t >= o) ? tmp[t - o] : 0;
        __syncthreads();
        tmp[t] = x + y;
        __syncthreads();
    }
    if (t < nb) bsum[t] = tmp[t] - v;   // exclusive
}

// Phase C: finalize. Each block re-reads its chunk, block-local exclusive scan
// + bsum offset; writes row_off[] and rewrites counts[] as the scatter cursor.
__global__ void scan_final(int* __restrict__ counts, const int* __restrict__ bsum,
                           int* __restrict__ row_off, int n, int chunk, int e_total) {
    __shared__ int tsum[256];
    int b = blockIdx.x, t = threadIdx.x;
    int s = b * chunk, e = min(s + chunk, n);
    int per = (chunk + 255) / 256;
    int ts = min(s + t * per, e), te = min(ts + per, e);
    int acc = 0;
    for (int i = ts; i < te; ++i) acc += counts[i];
    tsum[t] = acc;
    __syncthreads();
    for (int o = 1; o < 256; o <<= 1) {
        int x = tsum[t];
        int y = (t >= o) ? tsum[t - o] : 0;
        __syncthreads();
        tsum[t] = x + y;
        __syncthreads();
    }
    int run = bsum[b] + ((t == 0) ? 0 : tsum[t - 1]);
    for (int i = ts; i < te; ++i) {
        int c = counts[i];
        row_off[i] = run;
        counts[i] = run;   // becomes scatter cursor (same-thread read-then-write)
        run += c;
    }
    if (b == 0 && t == 0) row_off[n] = e_total;
}

__global__ void scatter_kernel(const int* __restrict__ src, const int* __restrict__ dst, int e,
                               int* __restrict__ cursor, int* __restrict__ csr_src) {
    int stride = gridDim.x * blockDim.x;
    for (int i = blockIdx.x * blockDim.x + threadIdx.x; i < e; i += stride) {
        int pos = atomicAdd(&cursor[dst[i]], 1);
        csr_src[pos] = src[i];
    }
}

// ---------------- GEMM + attention dots ----------------
// h[v][j] = sum_k x[v][k] * W[k][j];  el[v]=h[v].al;  er[v]=h[v].ar
// One wave per 4 nodes; lane = output feature. Each ds_read of W is shared by
// 4 fma chains (LDS pipe was the bottleneck at 1 node/wave: 5.8cyc/ds_read).
template <int K>
__global__ void gemm_attn_kernel(const float* __restrict__ x, const float* __restrict__ W,
                                 const float* __restrict__ al, const float* __restrict__ ar,
                                 float* __restrict__ h, float* __restrict__ el,
                                 float* __restrict__ er, int n) {
    __shared__ float Wl[K * 64];
    for (int i = threadIdx.x; i < K * 64; i += blockDim.x) Wl[i] = W[i];
    __syncthreads();
    int lane = threadIdx.x & 63;
    int gwave = (blockIdx.x * blockDim.x + threadIdx.x) >> 6;
    int nwaves = (gridDim.x * blockDim.x) >> 6;
    float a_l = al[lane], a_r = ar[lane];
    for (int v = gwave * 4; v < n; v += nwaves * 4) {
        int i1 = min(v + 1, n - 1), i2 = min(v + 2, n - 1), i3 = min(v + 3, n - 1);
        const float* x0p = x + (size_t)v * K;
        const float* x1p = x + (size_t)i1 * K;
        const float* x2p = x + (size_t)i2 * K;
        const float* x3p = x + (size_t)i3 * K;
        float x0a = x0p[lane], x1a = x1p[lane], x2a = x2p[lane], x3a = x3p[lane];
        float a0 = 0.f, a1 = 0.f, a2 = 0.f, a3 = 0.f;
#pragma unroll
        for (int k = 0; k < 64; ++k) {
            float w = Wl[k * 64 + lane];
            a0 = fmaf(readlane_f(x0a, k), w, a0);
            a1 = fmaf(readlane_f(x1a, k), w, a1);
            a2 = fmaf(readlane_f(x2a, k), w, a2);
            a3 = fmaf(readlane_f(x3a, k), w, a3);
        }
        if (K > 64) {
            float x0b = x0p[64 + lane], x1b = x1p[64 + lane];
            float x2b = x2p[64 + lane], x3b = x3p[64 + lane];
#pragma unroll
            for (int k = 0; k < 64; ++k) {
                float w = Wl[(64 + k) * 64 + lane];
                a0 = fmaf(readlane_f(x0b, k), w, a0);
                a1 = fmaf(readlane_f(x1b, k), w, a1);
                a2 = fmaf(readlane_f(x2b, k), w, a2);
                a3 = fmaf(readlane_f(x3b, k), w, a3);
            }
        }
        float accs[4] = {a0, a1, a2, a3};
        int idx[4] = {v, i1, i2, i3};
#pragma unroll
        for (int u = 0; u < 4; ++u) {
            if (v + u < n) {
                float a = accs[u];
                h[(size_t)(v + u) * 64 + lane] = a;
                float pl = a * a_l, pr = a * a_r;
#pragma unroll
                for (int off = 32; off > 0; off >>= 1) {
                    pl += __shfl_down(pl, off);
                    pr += __shfl_down(pr, off);
                }
                if (lane == 0) { el[idx[u]] = pl; er[idx[u]] = pr; }
            }
        }
    }
}

// ---------------- softmax-aggregate ----------------
__global__ void agg_kernel(const int* __restrict__ row_off, const int* __restrict__ csr_src,
                           const float* __restrict__ h, const float* __restrict__ el,
                           const float* __restrict__ er, const float* __restrict__ bias,
                           float* __restrict__ out, int n, int do_relu) {
    int lane = threadIdx.x & 63;
    int gwave = (blockIdx.x * blockDim.x + threadIdx.x) >> 6;
    int nwaves = (gridDim.x * blockDim.x) >> 6;
    float b = bias[lane];
    for (int v = gwave; v < n; v += nwaves) {
        int rs = row_off[v], re = row_off[v + 1];
        float er_v = er[v];
        float acc = 0.f, ssum = 0.f;
        for (int base = rs; base < re; base += 64) {
            int cnt = min(64, re - base);
            int s_e = 0;
            float ex = 0.f;
            if (lane < cnt) {
                s_e = csr_src[base + lane];
                float ev = el[s_e] + er_v;
                ev = (ev >= 0.f) ? ev : NEG_SLOPE * ev;
                ex = __expf(ev);
            }
            float cs = ex;
#pragma unroll
            for (int off = 32; off > 0; off >>= 1) cs += __shfl_xor(cs, off);
            ssum += cs;
            for (int j = 0; j < cnt; ++j) {
                int sj = readlane_i(s_e, j);
                float exj = readlane_f(ex, j);
                acc = fmaf(exj, h[(size_t)sj * 64 + lane], acc);
            }
        }
        float o = (re > rs) ? (acc / ssum + b) : b;
        if (do_relu) o = fmaxf(o, 0.f);
        out[(size_t)v * 64 + lane] = o;
    }
}

extern "C" void kernel_launch(void* const* d_in, const int* in_sizes, int n_in,
                              void* d_out, int out_size, void* d_ws, size_t ws_size,
                              hipStream_t stream) {
    (void)n_in; (void)out_size; (void)ws_size;
    const float* features = (const float*)d_in[0];
    // d_in[1] = edge_weights, unused by the reference forward
    const int*   src = (const int*)d_in[2];
    const int*   dst = (const int*)d_in[3];
    const float* W1  = (const float*)d_in[4];
    const float* al1 = (const float*)d_in[5];
    const float* ar1 = (const float*)d_in[6];
    const float* b1  = (const float*)d_in[7];
    const float* W2  = (const float*)d_in[8];
    const float* al2 = (const float*)d_in[9];
    const float* ar2 = (const float*)d_in[10];
    const float* b2  = (const float*)d_in[11];

    const int n = in_sizes[0] / 128;   // 100000
    const int e = in_sizes[2];         // 1600000
    float* out = (float*)d_out;

    // workspace carve-up (~59 MB)
    char* p = (char*)d_ws;
    auto alloc = [&](size_t bytes) -> char* {
        char* q = p;
        p += (bytes + 255) & ~(size_t)255;
        return q;
    };
    int*   counts  = (int*)alloc((size_t)n * 4);          // counts -> cursor
    int*   row_off = (int*)alloc((size_t)(n + 1) * 4);
    int*   csr_src = (int*)alloc((size_t)e * 4);
    float* h       = (float*)alloc((size_t)n * 64 * 4);   // layer GEMM out (reused)
    float* hr      = (float*)alloc((size_t)n * 64 * 4);   // relu(agg1) = layer2 input
    float* el      = (float*)alloc((size_t)n * 4);
    float* er      = (float*)alloc((size_t)n * 4);
    int*   bsum    = (int*)alloc(256 * 4);

    const int chunk = (n + 255) / 256;

    // CSR by dst (shared by both layers)
    hipMemsetAsync(counts, 0, (size_t)n * 4, stream);
    hist_kernel<<<2048, 256, 0, stream>>>(dst, e, counts);
    scan_block_sum<<<256, 256, 0, stream>>>(counts, bsum, n, chunk);
    scan_bsum<<<1, 256, 0, stream>>>(bsum, 256);
    scan_final<<<256, 256, 0, stream>>>(counts, bsum, row_off, n, chunk, e);
    scatter_kernel<<<2048, 256, 0, stream>>>(src, dst, e, counts, csr_src);

    // layer 1
    gemm_attn_kernel<128><<<512, 256, 0, stream>>>(features, W1, al1, ar1, h, el, er, n);
    agg_kernel<<<1024, 256, 0, stream>>>(row_off, csr_src, h, el, er, b1, hr, n, 1);

    // layer 2
    gemm_attn_kernel<64><<<512, 256, 0, stream>>>(hr, W2, al2, ar2, h, el, er, n);
    agg_kernel<<<1024, 256, 0, stream>>>(row_off, csr_src, h, el, er, b2, out, n, 0);
}

// Round 3
// 585.314 us; speedup vs baseline: 1.8471x; 1.6516x over previous
//
#include <hip/hip_runtime.h>

#define NEG_SLOPE 0.2f

__device__ inline float readlane_f(float v, int l) {
    return __int_as_float(__builtin_amdgcn_readlane(__float_as_int(v), l));
}
__device__ inline int readlane_i(int v, int l) {
    return __builtin_amdgcn_readlane(v, l);
}
__device__ inline int rfl_i(int v) { return __builtin_amdgcn_readfirstlane(v); }

// ---------------- CSR build ----------------

__global__ void hist_kernel(const int* __restrict__ dst, int e, int* __restrict__ counts) {
    int stride = gridDim.x * blockDim.x;
    for (int i = blockIdx.x * blockDim.x + threadIdx.x; i < e; i += stride)
        atomicAdd(&counts[dst[i]], 1);
}

__global__ void scan_block_sum(const int* __restrict__ counts, int* __restrict__ bsum,
                               int n, int chunk) {
    __shared__ int red[256];
    int b = blockIdx.x, t = threadIdx.x;
    int s = b * chunk, e = min(s + chunk, n);
    int acc = 0;
    for (int i = s + t; i < e; i += 256) acc += counts[i];
    red[t] = acc;
    __syncthreads();
    for (int o = 128; o > 0; o >>= 1) {
        if (t < o) red[t] += red[t + o];
        __syncthreads();
    }
    if (t == 0) bsum[b] = red[0];
}

__global__ void scan_bsum(int* __restrict__ bsum, int nb) {
    __shared__ int tmp[256];
    int t = threadIdx.x;
    int v = (t < nb) ? bsum[t] : 0;
    tmp[t] = v;
    __syncthreads();
    for (int o = 1; o < 256; o <<= 1) {
        int x = tmp[t];
        int y = (t >= o) ? tmp[t - o] : 0;
        __syncthreads();
        tmp[t] = x + y;
        __syncthreads();
    }
    if (t < nb) bsum[t] = tmp[t] - v;   // exclusive
}

__global__ void scan_final(int* __restrict__ counts, const int* __restrict__ bsum,
                           int* __restrict__ row_off, int n, int chunk, int e_total) {
    __shared__ int tsum[256];
    int b = blockIdx.x, t = threadIdx.x;
    int s = b * chunk, e = min(s + chunk, n);
    int per = (chunk + 255) / 256;
    int ts = min(s + t * per, e), te = min(ts + per, e);
    int acc = 0;
    for (int i = ts; i < te; ++i) acc += counts[i];
    tsum[t] = acc;
    __syncthreads();
    for (int o = 1; o < 256; o <<= 1) {
        int x = tsum[t];
        int y = (t >= o) ? tsum[t - o] : 0;
        __syncthreads();
        tsum[t] = x + y;
        __syncthreads();
    }
    int run = bsum[b] + ((t == 0) ? 0 : tsum[t - 1]);
    for (int i = ts; i < te; ++i) {
        int c = counts[i];
        row_off[i] = run;
        counts[i] = run;   // becomes scatter cursor
        run += c;
    }
    if (b == 0 && t == 0) row_off[n] = e_total;
}

__global__ void scatter_kernel(const int* __restrict__ src, const int* __restrict__ dst, int e,
                               int* __restrict__ cursor, int* __restrict__ csr_src) {
    int stride = gridDim.x * blockDim.x;
    for (int i = blockIdx.x * blockDim.x + threadIdx.x; i < e; i += stride) {
        int pos = atomicAdd(&cursor[dst[i]], 1);
        csr_src[pos] = src[i];
    }
}

// ---------------- GEMM + attention dots ----------------
// No LDS: each lane holds its W column (W[k][lane]) in VGPRs; x rows are
// wave-broadcast via readlane from coalesced per-lane loads. 8 nodes per wave
// = 8 independent fma chains (hides v_fma 4-cyc latency). 2 VALU/node-k, no
// lgkmcnt waits in the inner loop.
template <int K>
__global__ __launch_bounds__(256) void gemm_attn_kernel(
        const float* __restrict__ x, const float* __restrict__ W,
        const float* __restrict__ al, const float* __restrict__ ar,
        float* __restrict__ h, float* __restrict__ el,
        float* __restrict__ er, int n) {
    int lane = threadIdx.x & 63;
    int wave = rfl_i((int)((blockIdx.x * blockDim.x + threadIdx.x) >> 6));
    int v0 = wave * 8;
    if (v0 >= n) return;

    float Wreg[K];
#pragma unroll
    for (int k = 0; k < K; ++k) Wreg[k] = W[k * 64 + lane];
    float a_l = al[lane], a_r = ar[lane];

    float xa[8], xb[8];
#pragma unroll
    for (int u = 0; u < 8; ++u) {
        int v = min(v0 + u, n - 1);
        xa[u] = x[(size_t)v * K + lane];
        if (K > 64) xb[u] = x[(size_t)v * K + 64 + lane];
    }

    float acc[8] = {0.f, 0.f, 0.f, 0.f, 0.f, 0.f, 0.f, 0.f};
#pragma unroll
    for (int k = 0; k < 64; ++k) {
#pragma unroll
        for (int u = 0; u < 8; ++u)
            acc[u] = fmaf(readlane_f(xa[u], k), Wreg[k], acc[u]);
    }
    if (K > 64) {
#pragma unroll
        for (int k = 0; k < 64; ++k) {
#pragma unroll
            for (int u = 0; u < 8; ++u)
                acc[u] = fmaf(readlane_f(xb[u], k), Wreg[64 + k], acc[u]);
        }
    }

#pragma unroll
    for (int u = 0; u < 8; ++u) {
        int v = v0 + u;
        if (v < n) {
            float a = acc[u];
            h[(size_t)v * 64 + lane] = a;
            float pl = a * a_l, pr = a * a_r;
#pragma unroll
            for (int off = 32; off > 0; off >>= 1) {
                pl += __shfl_down(pl, off);
                pr += __shfl_down(pr, off);
            }
            if (lane == 0) { el[v] = pl; er[v] = pr; }
        }
    }
}

// ---------------- softmax-aggregate ----------------
// One wave per dst node; lane = feature. All indices forced wave-uniform via
// readfirstlane so the edge loop lives in SGPRs; inner loop unrolled x8 with
// zero-padding (lanes >= cnt have ex=0 -> padded fmas add 0, gather L1-hot
// h[0]) so 8 gathers are in flight per group.
__global__ __launch_bounds__(256) void agg_kernel(
        const int* __restrict__ row_off, const int* __restrict__ csr_src,
        const float* __restrict__ h, const float* __restrict__ el,
        const float* __restrict__ er, const float* __restrict__ bias,
        float* __restrict__ out, int n, int do_relu) {
    int lane = threadIdx.x & 63;
    int gwave = rfl_i((int)((blockIdx.x * blockDim.x + threadIdx.x) >> 6));
    int nwaves = (gridDim.x * blockDim.x) >> 6;
    float b = bias[lane];
    for (int v = gwave; v < n; v += nwaves) {
        int rs = rfl_i(row_off[v]), re = rfl_i(row_off[v + 1]);
        float er_v = er[v];
        float acc = 0.f, ssum = 0.f;
        for (int base = rs; base < re; base += 64) {
            int cnt = min(64, re - base);
            int s_e = 0;
            float ex = 0.f;
            if (lane < cnt) {
                s_e = csr_src[base + lane];
                float ev = el[s_e] + er_v;
                ev = (ev >= 0.f) ? ev : NEG_SLOPE * ev;
                ex = __expf(ev);
            }
            float cs = ex;
#pragma unroll
            for (int off = 32; off > 0; off >>= 1) cs += __shfl_xor(cs, off);
            ssum += cs;
            int cnt8 = (cnt + 7) & ~7;
            for (int j = 0; j < cnt8; j += 8) {
                int sj[8];
                float exj[8], hv[8];
#pragma unroll
                for (int u = 0; u < 8; ++u) {
                    sj[u] = readlane_i(s_e, j + u);
                    exj[u] = readlane_f(ex, j + u);
                    hv[u] = h[(size_t)sj[u] * 64 + lane];
                }
#pragma unroll
                for (int u = 0; u < 8; ++u)
                    acc = fmaf(exj[u], hv[u], acc);
            }
        }
        float o = (re > rs) ? (acc / ssum + b) : b;
        if (do_relu) o = fmaxf(o, 0.f);
        out[(size_t)v * 64 + lane] = o;
    }
}

extern "C" void kernel_launch(void* const* d_in, const int* in_sizes, int n_in,
                              void* d_out, int out_size, void* d_ws, size_t ws_size,
                              hipStream_t stream) {
    (void)n_in; (void)out_size; (void)ws_size;
    const float* features = (const float*)d_in[0];
    // d_in[1] = edge_weights, unused by the reference forward
    const int*   src = (const int*)d_in[2];
    const int*   dst = (const int*)d_in[3];
    const float* W1  = (const float*)d_in[4];
    const float* al1 = (const float*)d_in[5];
    const float* ar1 = (const float*)d_in[6];
    const float* b1  = (const float*)d_in[7];
    const float* W2  = (const float*)d_in[8];
    const float* al2 = (const float*)d_in[9];
    const float* ar2 = (const float*)d_in[10];
    const float* b2  = (const float*)d_in[11];

    const int n = in_sizes[0] / 128;   // 100000
    const int e = in_sizes[2];         // 1600000
    float* out = (float*)d_out;

    char* p = (char*)d_ws;
    auto alloc = [&](size_t bytes) -> char* {
        char* q = p;
        p += (bytes + 255) & ~(size_t)255;
        return q;
    };
    int*   counts  = (int*)alloc((size_t)n * 4);
    int*   row_off = (int*)alloc((size_t)(n + 1) * 4);
    int*   csr_src = (int*)alloc((size_t)e * 4);
    float* h       = (float*)alloc((size_t)n * 64 * 4);
    float* hr      = (float*)alloc((size_t)n * 64 * 4);
    float* el      = (float*)alloc((size_t)n * 4);
    float* er      = (float*)alloc((size_t)n * 4);
    int*   bsum    = (int*)alloc(256 * 4);

    const int chunk = (n + 255) / 256;

    // CSR by dst (shared by both layers)
    hipMemsetAsync(counts, 0, (size_t)n * 4, stream);
    hist_kernel<<<2048, 256, 0, stream>>>(dst, e, counts);
    scan_block_sum<<<256, 256, 0, stream>>>(counts, bsum, n, chunk);
    scan_bsum<<<1, 256, 0, stream>>>(bsum, 256);
    scan_final<<<256, 256, 0, stream>>>(counts, bsum, row_off, n, chunk, e);
    scatter_kernel<<<2048, 256, 0, stream>>>(src, dst, e, counts, csr_src);

    const int gemm_blocks = (n + 31) / 32;   // 4 waves/block x 8 nodes/wave

    // layer 1
    gemm_attn_kernel<128><<<gemm_blocks, 256, 0, stream>>>(features, W1, al1, ar1, h, el, er, n);
    agg_kernel<<<2048, 256, 0, stream>>>(row_off, csr_src, h, el, er, b1, hr, n, 1);

    // layer 2
    gemm_attn_kernel<64><<<gemm_blocks, 256, 0, stream>>>(hr, W2, al2, ar2, h, el, er, n);
    agg_kernel<<<2048, 256, 0, stream>>>(row_off, csr_src, h, el, er, b2, out, n, 0);
}

// Round 4
// 447.190 us; speedup vs baseline: 2.4176x; 1.3089x over previous
//
#include <hip/hip_runtime.h>

#define NEG_SLOPE 0.2f
#define BKT_SHIFT 9
#define BKT_SIZE (1 << BKT_SHIFT)
#define P1_EPT 16   // edges per thread in partition pass (chunk = 4096/block)

__device__ inline float readlane_f(float v, int l) {
    return __int_as_float(__builtin_amdgcn_readlane(__float_as_int(v), l));
}
__device__ inline int readlane_i(int v, int l) {
    return __builtin_amdgcn_readlane(v, l);
}
__device__ inline int rfl_i(int v) { return __builtin_amdgcn_readfirstlane(v); }

// ---------------- CSR build: histogram + scan ----------------

__global__ void hist_kernel(const int* __restrict__ dst, int e, int* __restrict__ counts) {
    int stride = gridDim.x * blockDim.x;
    for (int i = blockIdx.x * blockDim.x + threadIdx.x; i < e; i += stride)
        atomicAdd(&counts[dst[i]], 1);
}

__global__ void scan_block_sum(const int* __restrict__ counts, int* __restrict__ bsum,
                               int n, int chunk) {
    __shared__ int red[256];
    int b = blockIdx.x, t = threadIdx.x;
    int s = b * chunk, e = min(s + chunk, n);
    int acc = 0;
    for (int i = s + t; i < e; i += 256) acc += counts[i];
    red[t] = acc;
    __syncthreads();
    for (int o = 128; o > 0; o >>= 1) {
        if (t < o) red[t] += red[t + o];
        __syncthreads();
    }
    if (t == 0) bsum[b] = red[0];
}

__global__ void scan_bsum(int* __restrict__ bsum, int nb) {
    __shared__ int tmp[256];
    int t = threadIdx.x;
    int v = (t < nb) ? bsum[t] : 0;
    tmp[t] = v;
    __syncthreads();
    for (int o = 1; o < 256; o <<= 1) {
        int x = tmp[t];
        int y = (t >= o) ? tmp[t - o] : 0;
        __syncthreads();
        tmp[t] = x + y;
        __syncthreads();
    }
    if (t < nb) bsum[t] = tmp[t] - v;   // exclusive
}

__global__ void scan_final(const int* __restrict__ counts, const int* __restrict__ bsum,
                           int* __restrict__ row_off, int n, int chunk, int e_total) {
    __shared__ int tsum[256];
    int b = blockIdx.x, t = threadIdx.x;
    int s = b * chunk, e = min(s + chunk, n);
    int per = (chunk + 255) / 256;
    int ts = min(s + t * per, e), te = min(ts + per, e);
    int acc = 0;
    for (int i = ts; i < te; ++i) acc += counts[i];
    tsum[t] = acc;
    __syncthreads();
    for (int o = 1; o < 256; o <<= 1) {
        int x = tsum[t];
        int y = (t >= o) ? tsum[t - o] : 0;
        __syncthreads();
        tsum[t] = x + y;
        __syncthreads();
    }
    int run = bsum[b] + ((t == 0) ? 0 : tsum[t - 1]);
    for (int i = ts; i < te; ++i) {
        row_off[i] = run;
        run += counts[i];
    }
    if (b == 0 && t == 0) row_off[n] = e_total;
}

// ---------------- CSR build: two-level bucketed scatter ----------------
// Direct scatter wrote 107MB HBM for a 6.4MB array (random 4B stores -> full
// line writebacks per store, x8 XCDs). Two-level fix: coarse partition into
// dst>>9 buckets with per-block LDS ranking (writes cluster ~21 edges/bucket
// per chunk), then per-bucket fine sort whose write window (~26KB) is
// L2-resident -> full-line writebacks only.

__global__ void init_gcur(const int* __restrict__ row_off, int* __restrict__ gcur,
                          int n, int nbkt) {
    int t = blockIdx.x * blockDim.x + threadIdx.x;
    if (t < nbkt) gcur[t] = row_off[min(t << BKT_SHIFT, n)];
}

__global__ __launch_bounds__(256) void partition_kernel(
        const int* __restrict__ src, const int* __restrict__ dst, int e,
        int* __restrict__ gcur, int2* __restrict__ part, int nbkt) {
    __shared__ int cnt[256];
    __shared__ int base_l[256];
    int t = threadIdx.x;
    int cb = blockIdx.x * (256 * P1_EPT);
    if (t < nbkt) cnt[t] = 0;
    __syncthreads();
    int sr[P1_EPT], ds[P1_EPT], rk[P1_EPT];
#pragma unroll
    for (int i = 0; i < P1_EPT; ++i) {
        int eid = cb + t + i * 256;
        if (eid < e) {
            sr[i] = src[eid];
            ds[i] = dst[eid];
            rk[i] = atomicAdd(&cnt[ds[i] >> BKT_SHIFT], 1);
        } else {
            rk[i] = -1;
        }
    }
    __syncthreads();
    if (t < nbkt && cnt[t] > 0) base_l[t] = atomicAdd(&gcur[t], cnt[t]);
    __syncthreads();
#pragma unroll
    for (int i = 0; i < P1_EPT; ++i) {
        if (rk[i] >= 0) {
            int b = ds[i] >> BKT_SHIFT;
            part[base_l[b] + rk[i]] = make_int2(sr[i], ds[i]);
        }
    }
}

__global__ __launch_bounds__(256) void finesort_kernel(
        const int2* __restrict__ part, const int* __restrict__ row_off,
        int* __restrict__ csr_src, int n) {
    __shared__ int cur[BKT_SIZE];
    __shared__ int rofl[BKT_SIZE];
    int b = blockIdx.x, t = threadIdx.x;
    int d0 = b << BKT_SHIFT;
    int dlim = min(d0 + BKT_SIZE, n);
    for (int i = t; i < BKT_SIZE; i += 256) {
        cur[i] = 0;
        rofl[i] = (d0 + i < n) ? row_off[d0 + i] : 0;
    }
    __syncthreads();
    int s = row_off[d0];
    int eend = row_off[dlim];
    for (int i = s + t; i < eend; i += 256) {
        int2 p = part[i];
        int local = p.y - d0;
        int r = atomicAdd(&cur[local], 1);
        csr_src[rofl[local] + r] = p.x;
    }
}

// ---------------- GEMM + attention dots ----------------
// W in LDS (Wl[k*64+lane]: 2-way bank alias = free). 8 nodes/wave = 8
// independent fma chains; x rows broadcast via readlane. Per node-k: exactly
// readlane+fma (2 VALU). No per-lane W registers (the register version spilled
// W into AGPRs -> v_accvgpr_read per use, 3x VALU, 2 waves/SIMD).
template <int K>
__global__ __launch_bounds__(256) void gemm_attn_kernel(
        const float* __restrict__ x, const float* __restrict__ W,
        const float* __restrict__ al, const float* __restrict__ ar,
        float* __restrict__ h, float* __restrict__ el,
        float* __restrict__ er, int n) {
    __shared__ float Wl[K * 64];
    for (int i = threadIdx.x; i < K * 64; i += 256) Wl[i] = W[i];
    __syncthreads();
    int lane = threadIdx.x & 63;
    int wave = (int)((blockIdx.x * blockDim.x + threadIdx.x) >> 6);
    int v0 = wave * 8;
    if (v0 >= n) return;
    float a_l = al[lane], a_r = ar[lane];

    float xa[8], xb[8];
#pragma unroll
    for (int u = 0; u < 8; ++u) {
        int v = min(v0 + u, n - 1);
        xa[u] = x[(size_t)v * K + lane];
        if (K > 64) xb[u] = x[(size_t)v * K + 64 + lane];
    }

    float acc[8] = {0.f, 0.f, 0.f, 0.f, 0.f, 0.f, 0.f, 0.f};
#pragma unroll 16
    for (int k = 0; k < 64; ++k) {
        float w = Wl[k * 64 + lane];
#pragma unroll
        for (int u = 0; u < 8; ++u)
            acc[u] = fmaf(readlane_f(xa[u], k), w, acc[u]);
    }
    if (K > 64) {
#pragma unroll 16
        for (int k = 0; k < 64; ++k) {
            float w = Wl[(64 + k) * 64 + lane];
#pragma unroll
            for (int u = 0; u < 8; ++u)
                acc[u] = fmaf(readlane_f(xb[u], k), w, acc[u]);
        }
    }

#pragma unroll
    for (int u = 0; u < 8; ++u) {
        int v = v0 + u;
        if (v < n) {
            float a = acc[u];
            h[(size_t)v * 64 + lane] = a;
            float pl = a * a_l, pr = a * a_r;
#pragma unroll
            for (int off = 32; off > 0; off >>= 1) {
                pl += __shfl_down(pl, off);
                pr += __shfl_down(pr, off);
            }
            if (lane == 0) { el[v] = pl; er[v] = pr; }
        }
    }
}

// ---------------- softmax-aggregate ----------------
__global__ __launch_bounds__(256) void agg_kernel(
        const int* __restrict__ row_off, const int* __restrict__ csr_src,
        const float* __restrict__ h, const float* __restrict__ el,
        const float* __restrict__ er, const float* __restrict__ bias,
        float* __restrict__ out, int n, int do_relu) {
    int lane = threadIdx.x & 63;
    int gwave = rfl_i((int)((blockIdx.x * blockDim.x + threadIdx.x) >> 6));
    int nwaves = (gridDim.x * blockDim.x) >> 6;
    float b = bias[lane];
    for (int v = gwave; v < n; v += nwaves) {
        int rs = rfl_i(row_off[v]), re = rfl_i(row_off[v + 1]);
        float er_v = er[v];
        float acc = 0.f, ssum = 0.f;
        for (int base = rs; base < re; base += 64) {
            int cnt = min(64, re - base);
            int s_e = 0;
            float ex = 0.f;
            if (lane < cnt) {
                s_e = csr_src[base + lane];
                float ev = el[s_e] + er_v;
                ev = (ev >= 0.f) ? ev : NEG_SLOPE * ev;
                ex = __expf(ev);
            }
            float cs = ex;
#pragma unroll
            for (int off = 32; off > 0; off >>= 1) cs += __shfl_xor(cs, off);
            ssum += cs;
            int cnt8 = (cnt + 7) & ~7;
            for (int j = 0; j < cnt8; j += 8) {
                int sj[8];
                float exj[8], hv[8];
#pragma unroll
                for (int u = 0; u < 8; ++u) {
                    sj[u] = readlane_i(s_e, j + u);
                    exj[u] = readlane_f(ex, j + u);
                    hv[u] = h[(size_t)sj[u] * 64 + lane];
                }
#pragma unroll
                for (int u = 0; u < 8; ++u)
                    acc = fmaf(exj[u], hv[u], acc);
            }
        }
        float o = (re > rs) ? (acc / ssum + b) : b;
        if (do_relu) o = fmaxf(o, 0.f);
        out[(size_t)v * 64 + lane] = o;
    }
}

extern "C" void kernel_launch(void* const* d_in, const int* in_sizes, int n_in,
                              void* d_out, int out_size, void* d_ws, size_t ws_size,
                              hipStream_t stream) {
    (void)n_in; (void)out_size; (void)ws_size;
    const float* features = (const float*)d_in[0];
    // d_in[1] = edge_weights, unused by the reference forward
    const int*   src = (const int*)d_in[2];
    const int*   dst = (const int*)d_in[3];
    const float* W1  = (const float*)d_in[4];
    const float* al1 = (const float*)d_in[5];
    const float* ar1 = (const float*)d_in[6];
    const float* b1  = (const float*)d_in[7];
    const float* W2  = (const float*)d_in[8];
    const float* al2 = (const float*)d_in[9];
    const float* ar2 = (const float*)d_in[10];
    const float* b2  = (const float*)d_in[11];

    const int n = in_sizes[0] / 128;   // 100000
    const int e = in_sizes[2];         // 1600000
    float* out = (float*)d_out;

    char* p = (char*)d_ws;
    auto alloc = [&](size_t bytes) -> char* {
        char* q = p;
        p += (bytes + 255) & ~(size_t)255;
        return q;
    };
    int*   counts  = (int*)alloc((size_t)n * 4);
    int*   row_off = (int*)alloc((size_t)(n + 1) * 4);
    int*   csr_src = (int*)alloc((size_t)e * 4);
    float* h       = (float*)alloc((size_t)n * 64 * 4);
    float* hr      = (float*)alloc((size_t)n * 64 * 4);
    float* el      = (float*)alloc((size_t)n * 4);
    float* er      = (float*)alloc((size_t)n * 4);
    int*   gcur    = (int*)alloc(256 * 4);
    int*   bsum    = (int*)alloc(256 * 4);
    // part (e int2 = 12.8MB) aliases hr (25.6MB): consumed by finesort before
    // agg1 produces hr.
    int2*  part    = (int2*)hr;

    const int chunk = (n + 255) / 256;
    const int nbkt = (n + BKT_SIZE - 1) >> BKT_SHIFT;   // 196

    // CSR by dst (shared by both layers)
    hipMemsetAsync(counts, 0, (size_t)n * 4, stream);
    hist_kernel<<<2048, 256, 0, stream>>>(dst, e, counts);
    scan_block_sum<<<256, 256, 0, stream>>>(counts, bsum, n, chunk);
    scan_bsum<<<1, 256, 0, stream>>>(bsum, 256);
    scan_final<<<256, 256, 0, stream>>>(counts, bsum, row_off, n, chunk, e);
    init_gcur<<<1, 256, 0, stream>>>(row_off, gcur, n, nbkt);
    partition_kernel<<<(e + 256 * P1_EPT - 1) / (256 * P1_EPT), 256, 0, stream>>>(
        src, dst, e, gcur, part, nbkt);
    finesort_kernel<<<nbkt, 256, 0, stream>>>(part, row_off, csr_src, n);

    const int gemm_blocks = (n + 31) / 32;   // 4 waves/block x 8 nodes/wave

    // layer 1
    gemm_attn_kernel<128><<<gemm_blocks, 256, 0, stream>>>(features, W1, al1, ar1, h, el, er, n);
    agg_kernel<<<2048, 256, 0, stream>>>(row_off, csr_src, h, el, er, b1, hr, n, 1);

    // layer 2
    gemm_attn_kernel<64><<<gemm_blocks, 256, 0, stream>>>(hr, W2, al2, ar2, h, el, er, n);
    agg_kernel<<<2048, 256, 0, stream>>>(row_off, csr_src, h, el, er, b2, out, n, 0);
}

// Round 5
// 372.198 us; speedup vs baseline: 2.9047x; 1.2015x over previous
//
#include <hip/hip_runtime.h>

#define NEG_SLOPE 0.2f
#define BKT_SHIFT 9
#define BKT_SIZE (1 << BKT_SHIFT)
#define P1_EPT 16   // edges per thread in partition pass

typedef __attribute__((ext_vector_type(8))) short short8;
typedef __attribute__((ext_vector_type(4))) float float4v;

__device__ inline float readlane_f(float v, int l) {
    return __int_as_float(__builtin_amdgcn_readlane(__float_as_int(v), l));
}
__device__ inline int readlane_i(int v, int l) {
    return __builtin_amdgcn_readlane(v, l);
}
__device__ inline int rfl_i(int v) { return __builtin_amdgcn_readfirstlane(v); }

// round-to-nearest-even fp32 -> bf16
__device__ inline unsigned short f2bf(float f) {
    unsigned u = __float_as_uint(f);
    unsigned r = u + 0x7FFFu + ((u >> 16) & 1u);
    return (unsigned short)(r >> 16);
}
__device__ inline float bf2f(unsigned short b) {
    return __uint_as_float(((unsigned)b) << 16);
}

// ---------------- CSR build: histogram + scan ----------------

__global__ void hist_kernel(const int* __restrict__ dst, int e, int* __restrict__ counts) {
    int stride = gridDim.x * blockDim.x;
    for (int i = blockIdx.x * blockDim.x + threadIdx.x; i < e; i += stride)
        atomicAdd(&counts[dst[i]], 1);
}

__global__ void scan_block_sum(const int* __restrict__ counts, int* __restrict__ bsum,
                               int n, int chunk) {
    __shared__ int red[256];
    int b = blockIdx.x, t = threadIdx.x;
    int s = b * chunk, e = min(s + chunk, n);
    int acc = 0;
    for (int i = s + t; i < e; i += 256) acc += counts[i];
    red[t] = acc;
    __syncthreads();
    for (int o = 128; o > 0; o >>= 1) {
        if (t < o) red[t] += red[t + o];
        __syncthreads();
    }
    if (t == 0) bsum[b] = red[0];
}

__global__ void scan_bsum(int* __restrict__ bsum, int nb) {
    __shared__ int tmp[256];
    int t = threadIdx.x;
    int v = (t < nb) ? bsum[t] : 0;
    tmp[t] = v;
    __syncthreads();
    for (int o = 1; o < 256; o <<= 1) {
        int x = tmp[t];
        int y = (t >= o) ? tmp[t - o] : 0;
        __syncthreads();
        tmp[t] = x + y;
        __syncthreads();
    }
    if (t < nb) bsum[t] = tmp[t] - v;   // exclusive
}

__global__ void scan_final(const int* __restrict__ counts, const int* __restrict__ bsum,
                           int* __restrict__ row_off, int n, int chunk, int e_total) {
    __shared__ int tsum[256];
    int b = blockIdx.x, t = threadIdx.x;
    int s = b * chunk, e = min(s + chunk, n);
    int per = (chunk + 255) / 256;
    int ts = min(s + t * per, e), te = min(ts + per, e);
    int acc = 0;
    for (int i = ts; i < te; ++i) acc += counts[i];
    tsum[t] = acc;
    __syncthreads();
    for (int o = 1; o < 256; o <<= 1) {
        int x = tsum[t];
        int y = (t >= o) ? tsum[t - o] : 0;
        __syncthreads();
        tsum[t] = x + y;
        __syncthreads();
    }
    int run = bsum[b] + ((t == 0) ? 0 : tsum[t - 1]);
    for (int i = ts; i < te; ++i) {
        row_off[i] = run;
        run += counts[i];
    }
    if (b == 0 && t == 0) row_off[n] = e_total;
}

// ---------------- CSR build: two-level bucketed scatter ----------------

__global__ void init_gcur(const int* __restrict__ row_off, int* __restrict__ gcur,
                          int n, int nbkt) {
    int t = blockIdx.x * blockDim.x + threadIdx.x;
    if (t < nbkt) gcur[t] = row_off[min(t << BKT_SHIFT, n)];
}

__global__ __launch_bounds__(256) void partition_kernel(
        const int* __restrict__ src, const int* __restrict__ dst, int e,
        int* __restrict__ gcur, int2* __restrict__ part, int nbkt) {
    __shared__ int cnt[256];
    __shared__ int base_l[256];
    int t = threadIdx.x;
    int cb = blockIdx.x * (256 * P1_EPT);
    if (t < nbkt) cnt[t] = 0;
    __syncthreads();
    int sr[P1_EPT], ds[P1_EPT], rk[P1_EPT];
#pragma unroll
    for (int i = 0; i < P1_EPT; ++i) {
        int eid = cb + t + i * 256;
        if (eid < e) {
            sr[i] = src[eid];
            ds[i] = dst[eid];
            rk[i] = atomicAdd(&cnt[ds[i] >> BKT_SHIFT], 1);
        } else {
            rk[i] = -1;
        }
    }
    __syncthreads();
    if (t < nbkt && cnt[t] > 0) base_l[t] = atomicAdd(&gcur[t], cnt[t]);
    __syncthreads();
#pragma unroll
    for (int i = 0; i < P1_EPT; ++i) {
        if (rk[i] >= 0) {
            int b = ds[i] >> BKT_SHIFT;
            part[base_l[b] + rk[i]] = make_int2(sr[i], ds[i]);
        }
    }
}

__global__ __launch_bounds__(256) void finesort_kernel(
        const int2* __restrict__ part, const int* __restrict__ row_off,
        int* __restrict__ csr_src, int n) {
    __shared__ int cur[BKT_SIZE];
    __shared__ int rofl[BKT_SIZE];
    int b = blockIdx.x, t = threadIdx.x;
    int d0 = b << BKT_SHIFT;
    int dlim = min(d0 + BKT_SIZE, n);
    for (int i = t; i < BKT_SIZE; i += 256) {
        cur[i] = 0;
        rofl[i] = (d0 + i < n) ? row_off[d0 + i] : 0;
    }
    __syncthreads();
    int s = row_off[d0];
    int eend = row_off[dlim];
    for (int i = s + t; i < eend; i += 256) {
        int2 p = part[i];
        int local = p.y - d0;
        int r = atomicAdd(&cur[local], 1);
        csr_src[rofl[local] + r] = p.x;
    }
}

// ---------------- W decomposition into MFMA frag order ----------------
// Frag order: index ((kt*4+fb)*64 + lane)*8 + j holds W[kt*32 + q*8 + j][fb*16 + c]
// (q=lane>>4, c=lane&15) -> B-frag load in GEMM = one ds_read_b128 per frag.
__global__ void wprep_kernel(const float* __restrict__ W, unsigned short* __restrict__ wh,
                             unsigned short* __restrict__ wl, int K) {
    int idx = blockIdx.x * blockDim.x + threadIdx.x;   // (kt*4+fb)*64 + lane
    int KT = K / 32;
    if (idx >= KT * 4 * 64) return;
    int lane = idx & 63;
    int fbkt = idx >> 6;
    int fb = fbkt & 3, kt = fbkt >> 2;
    int q = lane >> 4, c = lane & 15;
    for (int j = 0; j < 8; ++j) {
        float w = W[(kt * 32 + q * 8 + j) * 64 + fb * 16 + c];
        unsigned short hi = f2bf(w);
        wh[idx * 8 + j] = hi;
        wl[idx * 8 + j] = f2bf(w - bf2f(hi));
    }
}

// ---------------- MFMA GEMM + attention dots ----------------
// h[N,64] = x[N,K] @ W[K,64] via v_mfma_f32_16x16x32_bf16, bf16x3 split
// (xh@Wh + xl@Wh + xh@Wl; dropped xl@Wl ~2^-18 rel). One wave per 16-node
// tile, all 64 features (4 C-frags). A-layout A[m=lane&15][k=(lane>>4)*8+j],
// C-layout col=lane&15,row=(lane>>4)*4+reg (guide-verified m89/m91).
// el/er computed from C-frags with intra-16-lane shfl_xor reductions.
template <int KT>
__global__ __launch_bounds__(256) void gemm_mfma_kernel(
        const float* __restrict__ x, const unsigned short* __restrict__ wh,
        const unsigned short* __restrict__ wl,
        const float* __restrict__ al, const float* __restrict__ ar,
        float* __restrict__ h, float* __restrict__ el,
        float* __restrict__ er, int n) {
    constexpr int K = KT * 32;
    constexpr int WFRAG = KT * 4 * 64 * 8;   // shorts
    __shared__ unsigned short Wh[WFRAG];
    __shared__ unsigned short Wl[WFRAG];
    for (int i = threadIdx.x; i < WFRAG / 8; i += 256) {   // 16B per step
        ((float4*)Wh)[i] = ((const float4*)wh)[i];
        ((float4*)Wl)[i] = ((const float4*)wl)[i];
    }
    __syncthreads();

    int lane = threadIdx.x & 63;
    int q = lane >> 4, c = lane & 15;
    int wave = (int)((blockIdx.x * blockDim.x + threadIdx.x) >> 6);
    int nwaves = (gridDim.x * blockDim.x) >> 6;
    int ntiles = (n + 15) >> 4;

    float alv[4], arv[4];
#pragma unroll
    for (int fb = 0; fb < 4; ++fb) {
        alv[fb] = al[fb * 16 + c];
        arv[fb] = ar[fb * 16 + c];
    }

    for (int t = wave; t < ntiles; t += nwaves) {
        int v0 = t * 16;
        int row = min(v0 + c, n - 1);
        const float* xr = x + (size_t)row * K + q * 8;

        short8 Ah[KT], Al[KT];
#pragma unroll
        for (int kt = 0; kt < KT; ++kt) {
            float xv[8];
            *(float4*)&xv[0] = *(const float4*)(xr + kt * 32);
            *(float4*)&xv[4] = *(const float4*)(xr + kt * 32 + 4);
#pragma unroll
            for (int j = 0; j < 8; ++j) {
                unsigned short hi = f2bf(xv[j]);
                Ah[kt][j] = (short)hi;
                Al[kt][j] = (short)f2bf(xv[j] - bf2f(hi));
            }
        }

        float4v acc[4];
#pragma unroll
        for (int fb = 0; fb < 4; ++fb) acc[fb] = (float4v)0.f;

#pragma unroll
        for (int kt = 0; kt < KT; ++kt) {
#pragma unroll
            for (int fb = 0; fb < 4; ++fb) {
                short8 bh = *(const short8*)&Wh[((kt * 4 + fb) * 64 + lane) * 8];
                short8 bl = *(const short8*)&Wl[((kt * 4 + fb) * 64 + lane) * 8];
                acc[fb] = __builtin_amdgcn_mfma_f32_16x16x32_bf16(Ah[kt], bh, acc[fb], 0, 0, 0);
                acc[fb] = __builtin_amdgcn_mfma_f32_16x16x32_bf16(Al[kt], bh, acc[fb], 0, 0, 0);
                acc[fb] = __builtin_amdgcn_mfma_f32_16x16x32_bf16(Ah[kt], bl, acc[fb], 0, 0, 0);
            }
        }

#pragma unroll
        for (int r = 0; r < 4; ++r) {
            int v = v0 + q * 4 + r;
            float pl = 0.f, pr = 0.f;
            bool ok = (v < n);
#pragma unroll
            for (int fb = 0; fb < 4; ++fb) {
                float hv = acc[fb][r];
                if (ok) h[(size_t)v * 64 + fb * 16 + c] = hv;
                pl = fmaf(hv, alv[fb], pl);
                pr = fmaf(hv, arv[fb], pr);
            }
#pragma unroll
            for (int off = 8; off > 0; off >>= 1) {
                pl += __shfl_xor(pl, off);
                pr += __shfl_xor(pr, off);
            }
            if (ok && c == 0) { el[v] = pl; er[v] = pr; }
        }
    }
}

// ---------------- softmax-aggregate ----------------
__global__ __launch_bounds__(256) void agg_kernel(
        const int* __restrict__ row_off, const int* __restrict__ csr_src,
        const float* __restrict__ h, const float* __restrict__ el,
        const float* __restrict__ er, const float* __restrict__ bias,
        float* __restrict__ out, int n, int do_relu) {
    int lane = threadIdx.x & 63;
    int gwave = rfl_i((int)((blockIdx.x * blockDim.x + threadIdx.x) >> 6));
    int nwaves = (gridDim.x * blockDim.x) >> 6;
    float b = bias[lane];
    for (int v = gwave; v < n; v += nwaves) {
        int rs = rfl_i(row_off[v]), re = rfl_i(row_off[v + 1]);
        float er_v = er[v];
        float acc = 0.f, ssum = 0.f;
        for (int base = rs; base < re; base += 64) {
            int cnt = min(64, re - base);
            int s_e = 0;
            float ex = 0.f;
            if (lane < cnt) {
                s_e = csr_src[base + lane];
                float ev = el[s_e] + er_v;
                ev = (ev >= 0.f) ? ev : NEG_SLOPE * ev;
                ex = __expf(ev);
            }
            float cs = ex;
#pragma unroll
            for (int off = 32; off > 0; off >>= 1) cs += __shfl_xor(cs, off);
            ssum += cs;
            int cnt8 = (cnt + 7) & ~7;
            for (int j = 0; j < cnt8; j += 8) {
                int sj[8];
                float exj[8], hv[8];
#pragma unroll
                for (int u = 0; u < 8; ++u) {
                    sj[u] = readlane_i(s_e, j + u);
                    exj[u] = readlane_f(ex, j + u);
                    hv[u] = h[(size_t)sj[u] * 64 + lane];
                }
#pragma unroll
                for (int u = 0; u < 8; ++u)
                    acc = fmaf(exj[u], hv[u], acc);
            }
        }
        float o = (re > rs) ? (acc / ssum + b) : b;
        if (do_relu) o = fmaxf(o, 0.f);
        out[(size_t)v * 64 + lane] = o;
    }
}

extern "C" void kernel_launch(void* const* d_in, const int* in_sizes, int n_in,
                              void* d_out, int out_size, void* d_ws, size_t ws_size,
                              hipStream_t stream) {
    (void)n_in; (void)out_size; (void)ws_size;
    const float* features = (const float*)d_in[0];
    // d_in[1] = edge_weights, unused by the reference forward
    const int*   src = (const int*)d_in[2];
    const int*   dst = (const int*)d_in[3];
    const float* W1  = (const float*)d_in[4];
    const float* al1 = (const float*)d_in[5];
    const float* ar1 = (const float*)d_in[6];
    const float* b1  = (const float*)d_in[7];
    const float* W2  = (const float*)d_in[8];
    const float* al2 = (const float*)d_in[9];
    const float* ar2 = (const float*)d_in[10];
    const float* b2  = (const float*)d_in[11];

    const int n = in_sizes[0] / 128;   // 100000
    const int e = in_sizes[2];         // 1600000
    float* out = (float*)d_out;

    char* p = (char*)d_ws;
    auto alloc = [&](size_t bytes) -> char* {
        char* q = p;
        p += (bytes + 255) & ~(size_t)255;
        return q;
    };
    int*   counts  = (int*)alloc((size_t)n * 4);
    int*   row_off = (int*)alloc((size_t)(n + 1) * 4);
    int*   csr_src = (int*)alloc((size_t)e * 4);
    float* h       = (float*)alloc((size_t)n * 64 * 4);
    float* hr      = (float*)alloc((size_t)n * 64 * 4);
    float* el      = (float*)alloc((size_t)n * 4);
    float* er      = (float*)alloc((size_t)n * 4);
    int*   gcur    = (int*)alloc(256 * 4);
    int*   bsum    = (int*)alloc(256 * 4);
    unsigned short* w1h = (unsigned short*)alloc(4 * 4 * 64 * 8 * 2);
    unsigned short* w1l = (unsigned short*)alloc(4 * 4 * 64 * 8 * 2);
    unsigned short* w2h = (unsigned short*)alloc(2 * 4 * 64 * 8 * 2);
    unsigned short* w2l = (unsigned short*)alloc(2 * 4 * 64 * 8 * 2);
    // part (e int2 = 12.8MB) aliases hr (25.6MB): consumed by finesort before
    // agg1 produces hr.
    int2*  part    = (int2*)hr;

    const int chunk = (n + 255) / 256;
    const int nbkt = (n + BKT_SIZE - 1) >> BKT_SHIFT;   // 196

    // W decomposition (tiny, once per launch)
    wprep_kernel<<<4, 256, 0, stream>>>(W1, w1h, w1l, 128);
    wprep_kernel<<<2, 256, 0, stream>>>(W2, w2h, w2l, 64);

    // CSR by dst (shared by both layers)
    hipMemsetAsync(counts, 0, (size_t)n * 4, stream);
    hist_kernel<<<2048, 256, 0, stream>>>(dst, e, counts);
    scan_block_sum<<<256, 256, 0, stream>>>(counts, bsum, n, chunk);
    scan_bsum<<<1, 256, 0, stream>>>(bsum, 256);
    scan_final<<<256, 256, 0, stream>>>(counts, bsum, row_off, n, chunk, e);
    init_gcur<<<1, 256, 0, stream>>>(row_off, gcur, n, nbkt);
    partition_kernel<<<(e + 256 * P1_EPT - 1) / (256 * P1_EPT), 256, 0, stream>>>(
        src, dst, e, gcur, part, nbkt);
    finesort_kernel<<<nbkt, 256, 0, stream>>>(part, row_off, csr_src, n);

    // layer 1
    gemm_mfma_kernel<4><<<512, 256, 0, stream>>>(features, w1h, w1l, al1, ar1, h, el, er, n);
    agg_kernel<<<2048, 256, 0, stream>>>(row_off, csr_src, h, el, er, b1, hr, n, 1);

    // layer 2
    gemm_mfma_kernel<2><<<512, 256, 0, stream>>>(hr, w2h, w2l, al2, ar2, h, el, er, n);
    agg_kernel<<<2048, 256, 0, stream>>>(row_off, csr_src, h, el, er, b2, out, n, 0);
}

// Round 6
// 333.394 us; speedup vs baseline: 3.2428x; 1.1164x over previous
//
#include <hip/hip_runtime.h>

#define NEG_SLOPE 0.2f
#define BKT_SHIFT 9
#define BKT_SIZE (1 << BKT_SHIFT)
#define P1_EPT 16   // edges per thread in partition pass

typedef __attribute__((ext_vector_type(8))) short short8;
typedef __attribute__((ext_vector_type(4))) float float4v;

__device__ inline float readlane_f(float v, int l) {
    return __int_as_float(__builtin_amdgcn_readlane(__float_as_int(v), l));
}
__device__ inline int readlane_i(int v, int l) {
    return __builtin_amdgcn_readlane(v, l);
}
__device__ inline int rfl_i(int v) { return __builtin_amdgcn_readfirstlane(v); }

// round-to-nearest-even fp32 -> bf16
__device__ inline unsigned short f2bf(float f) {
    unsigned u = __float_as_uint(f);
    unsigned r = u + 0x7FFFu + ((u >> 16) & 1u);
    return (unsigned short)(r >> 16);
}
__device__ inline float bf2f(unsigned short b) {
    return __uint_as_float(((unsigned)b) << 16);
}

// ---------------- CSR build ----------------
// Old per-node global-atomic histogram wrote 50MB HBM (1.6M random RMW x 32B
// sector writeback). New scheme never does per-node global atomics: bucket
// histogram in LDS (one global atomic per block x bucket), tiny 196-scan,
// coarse partition (clustered writes), then per-bucket finesort that derives
// the per-node row_off slice in LDS and scatters within an L2-resident window.

__global__ __launch_bounds__(256) void bucket_hist(const int* __restrict__ dst, int e,
                                                   int* __restrict__ bkt_cnt, int nbkt) {
    __shared__ int lc[256];
    int t = threadIdx.x;
    lc[t] = 0;
    __syncthreads();
    int stride = gridDim.x * blockDim.x;
    for (int i = blockIdx.x * blockDim.x + t; i < e; i += stride)
        atomicAdd(&lc[dst[i] >> BKT_SHIFT], 1);
    __syncthreads();
    if (t < nbkt && lc[t]) atomicAdd(&bkt_cnt[t], lc[t]);
}

// 1 block x 256: exclusive scan of bucket counts -> bbase[0..nbkt], gcur.
__global__ void bkt_scan(const int* __restrict__ bkt_cnt, int* __restrict__ bbase,
                         int* __restrict__ gcur, int nbkt, int e_total) {
    __shared__ int tmp[256];
    int t = threadIdx.x;
    int v = (t < nbkt) ? bkt_cnt[t] : 0;
    tmp[t] = v;
    __syncthreads();
    for (int o = 1; o < 256; o <<= 1) {
        int x = tmp[t];
        int y = (t >= o) ? tmp[t - o] : 0;
        __syncthreads();
        tmp[t] = x + y;
        __syncthreads();
    }
    if (t < nbkt) {
        int ex = tmp[t] - v;
        bbase[t] = ex;
        gcur[t] = ex;
    }
    if (t == 0) bbase[nbkt] = e_total;
}

__global__ __launch_bounds__(256) void partition_kernel(
        const int* __restrict__ src, const int* __restrict__ dst, int e,
        int* __restrict__ gcur, int2* __restrict__ part, int nbkt) {
    __shared__ int cnt[256];
    __shared__ int base_l[256];
    int t = threadIdx.x;
    int cb = blockIdx.x * (256 * P1_EPT);
    if (t < nbkt) cnt[t] = 0;
    __syncthreads();
    int sr[P1_EPT], ds[P1_EPT], rk[P1_EPT];
#pragma unroll
    for (int i = 0; i < P1_EPT; ++i) {
        int eid = cb + t + i * 256;
        if (eid < e) {
            sr[i] = src[eid];
            ds[i] = dst[eid];
            rk[i] = atomicAdd(&cnt[ds[i] >> BKT_SHIFT], 1);
        } else {
            rk[i] = -1;
        }
    }
    __syncthreads();
    if (t < nbkt && cnt[t] > 0) base_l[t] = atomicAdd(&gcur[t], cnt[t]);
    __syncthreads();
#pragma unroll
    for (int i = 0; i < P1_EPT; ++i) {
        if (rk[i] >= 0) {
            int b = ds[i] >> BKT_SHIFT;
            part[base_l[b] + rk[i]] = make_int2(sr[i], ds[i]);
        }
    }
}

// Per bucket (512 dst nodes): count per-dst in LDS, block-scan 512, write this
// bucket's row_off slice (coalesced), then scatter within the bucket's
// csr window (~tens of KB -> L2-resident, full-line writebacks only).
__global__ __launch_bounds__(256) void finesort2(
        const int2* __restrict__ part, const int* __restrict__ bbase,
        int* __restrict__ row_off, int* __restrict__ csr_src, int n, int e_total) {
    __shared__ int cnt[BKT_SIZE];
    __shared__ int cur[BKT_SIZE];
    __shared__ int tmp[256];
    int b = blockIdx.x, t = threadIdx.x;
    int d0 = b << BKT_SHIFT;
    int dlim = min(d0 + BKT_SIZE, n);
    int nloc = dlim - d0;
    for (int i = t; i < BKT_SIZE; i += 256) cnt[i] = 0;
    __syncthreads();
    int base = bbase[b], bend = bbase[b + 1];
    for (int i = base + t; i < bend; i += 256)
        atomicAdd(&cnt[part[i].y - d0], 1);
    __syncthreads();
    // block-exclusive-scan of 512 counts: thread t owns elements 2t, 2t+1
    int c0 = cnt[2 * t], c1 = cnt[2 * t + 1];
    int s = c0 + c1;
    tmp[t] = s;
    __syncthreads();
    for (int o = 1; o < 256; o <<= 1) {
        int x = tmp[t];
        int y = (t >= o) ? tmp[t - o] : 0;
        __syncthreads();
        tmp[t] = x + y;
        __syncthreads();
    }
    int excl = tmp[t] - s;
    cur[2 * t] = base + excl;
    cur[2 * t + 1] = base + excl + c0;
    __syncthreads();
    for (int i = t; i < nloc; i += 256) row_off[d0 + i] = cur[i];
    if (dlim == n && t == 0) row_off[n] = e_total;
    __syncthreads();   // row_off reads of cur[] must finish before scatter mutates cur
    for (int i = base + t; i < bend; i += 256) {
        int2 p = part[i];
        int pos = atomicAdd(&cur[p.y - d0], 1);
        csr_src[pos] = p.x;
    }
}

// ---------------- W decomposition into MFMA frag order ----------------
// Frag order: index ((kt*4+fb)*64 + lane)*8 + j holds W[kt*32 + q*8 + j][fb*16 + c]
// (q=lane>>4, c=lane&15) -> B-frag load in GEMM = one ds_read_b128 per frag.
__global__ void wprep_kernel(const float* __restrict__ W, unsigned short* __restrict__ wh,
                             unsigned short* __restrict__ wl, int K) {
    int idx = blockIdx.x * blockDim.x + threadIdx.x;   // (kt*4+fb)*64 + lane
    int KT = K / 32;
    if (idx >= KT * 4 * 64) return;
    int lane = idx & 63;
    int fbkt = idx >> 6;
    int fb = fbkt & 3, kt = fbkt >> 2;
    int q = lane >> 4, c = lane & 15;
    for (int j = 0; j < 8; ++j) {
        float w = W[(kt * 32 + q * 8 + j) * 64 + fb * 16 + c];
        unsigned short hi = f2bf(w);
        wh[idx * 8 + j] = hi;
        wl[idx * 8 + j] = f2bf(w - bf2f(hi));
    }
}

// ---------------- MFMA GEMM + attention dots ----------------
// h[N,64] = x[N,K] @ W[K,64] via v_mfma_f32_16x16x32_bf16, bf16x3 split
// (xh@Wh + xl@Wh + xh@Wl; dropped xl@Wl ~2^-18 rel). One wave per 16-node
// tile, all 64 features (4 C-frags). A-layout A[m=lane&15][k=(lane>>4)*8+j],
// C-layout col=lane&15,row=(lane>>4)*4+reg (guide-verified m89/m91).
template <int KT>
__global__ __launch_bounds__(256) void gemm_mfma_kernel(
        const float* __restrict__ x, const unsigned short* __restrict__ wh,
        const unsigned short* __restrict__ wl,
        const float* __restrict__ al, const float* __restrict__ ar,
        float* __restrict__ h, float* __restrict__ el,
        float* __restrict__ er, int n) {
    constexpr int K = KT * 32;
    constexpr int WFRAG = KT * 4 * 64 * 8;   // shorts
    __shared__ unsigned short Wh[WFRAG];
    __shared__ unsigned short Wl[WFRAG];
    for (int i = threadIdx.x; i < WFRAG / 8; i += 256) {   // 16B per step
        ((float4*)Wh)[i] = ((const float4*)wh)[i];
        ((float4*)Wl)[i] = ((const float4*)wl)[i];
    }
    __syncthreads();

    int lane = threadIdx.x & 63;
    int q = lane >> 4, c = lane & 15;
    int wave = (int)((blockIdx.x * blockDim.x + threadIdx.x) >> 6);
    int nwaves = (gridDim.x * blockDim.x) >> 6;
    int ntiles = (n + 15) >> 4;

    float alv[4], arv[4];
#pragma unroll
    for (int fb = 0; fb < 4; ++fb) {
        alv[fb] = al[fb * 16 + c];
        arv[fb] = ar[fb * 16 + c];
    }

    for (int t = wave; t < ntiles; t += nwaves) {
        int v0 = t * 16;
        int row = min(v0 + c, n - 1);
        const float* xr = x + (size_t)row * K + q * 8;

        short8 Ah[KT], Al[KT];
#pragma unroll
        for (int kt = 0; kt < KT; ++kt) {
            float xv[8];
            *(float4*)&xv[0] = *(const float4*)(xr + kt * 32);
            *(float4*)&xv[4] = *(const float4*)(xr + kt * 32 + 4);
#pragma unroll
            for (int j = 0; j < 8; ++j) {
                unsigned short hi = f2bf(xv[j]);
                Ah[kt][j] = (short)hi;
                Al[kt][j] = (short)f2bf(xv[j] - bf2f(hi));
            }
        }

        float4v acc[4];
#pragma unroll
        for (int fb = 0; fb < 4; ++fb) acc[fb] = (float4v)0.f;

#pragma unroll
        for (int kt = 0; kt < KT; ++kt) {
#pragma unroll
            for (int fb = 0; fb < 4; ++fb) {
                short8 bh = *(const short8*)&Wh[((kt * 4 + fb) * 64 + lane) * 8];
                short8 bl = *(const short8*)&Wl[((kt * 4 + fb) * 64 + lane) * 8];
                acc[fb] = __builtin_amdgcn_mfma_f32_16x16x32_bf16(Ah[kt], bh, acc[fb], 0, 0, 0);
                acc[fb] = __builtin_amdgcn_mfma_f32_16x16x32_bf16(Al[kt], bh, acc[fb], 0, 0, 0);
                acc[fb] = __builtin_amdgcn_mfma_f32_16x16x32_bf16(Ah[kt], bl, acc[fb], 0, 0, 0);
            }
        }

#pragma unroll
        for (int r = 0; r < 4; ++r) {
            int v = v0 + q * 4 + r;
            float pl = 0.f, pr = 0.f;
            bool ok = (v < n);
#pragma unroll
            for (int fb = 0; fb < 4; ++fb) {
                float hv = acc[fb][r];
                if (ok) h[(size_t)v * 64 + fb * 16 + c] = hv;
                pl = fmaf(hv, alv[fb], pl);
                pr = fmaf(hv, arv[fb], pr);
            }
#pragma unroll
            for (int off = 8; off > 0; off >>= 1) {
                pl += __shfl_xor(pl, off);
                pr += __shfl_xor(pr, off);
            }
            if (ok && c == 0) { el[v] = pl; er[v] = pr; }
        }
    }
}

// ---------------- softmax-aggregate ----------------
__global__ __launch_bounds__(256) void agg_kernel(
        const int* __restrict__ row_off, const int* __restrict__ csr_src,
        const float* __restrict__ h, const float* __restrict__ el,
        const float* __restrict__ er, const float* __restrict__ bias,
        float* __restrict__ out, int n, int do_relu) {
    int lane = threadIdx.x & 63;
    int gwave = rfl_i((int)((blockIdx.x * blockDim.x + threadIdx.x) >> 6));
    int nwaves = (gridDim.x * blockDim.x) >> 6;
    float b = bias[lane];
    for (int v = gwave; v < n; v += nwaves) {
        int rs = rfl_i(row_off[v]), re = rfl_i(row_off[v + 1]);
        float er_v = er[v];
        float acc = 0.f, ssum = 0.f;
        for (int base = rs; base < re; base += 64) {
            int cnt = min(64, re - base);
            int s_e = 0;
            float ex = 0.f;
            if (lane < cnt) {
                s_e = csr_src[base + lane];
                float ev = el[s_e] + er_v;
                ev = (ev >= 0.f) ? ev : NEG_SLOPE * ev;
                ex = __expf(ev);
            }
            float cs = ex;
#pragma unroll
            for (int off = 32; off > 0; off >>= 1) cs += __shfl_xor(cs, off);
            ssum += cs;
            int cnt8 = (cnt + 7) & ~7;
            for (int j = 0; j < cnt8; j += 8) {
                int sj[8];
                float exj[8], hv[8];
#pragma unroll
                for (int u = 0; u < 8; ++u) {
                    sj[u] = readlane_i(s_e, j + u);
                    exj[u] = readlane_f(ex, j + u);
                    hv[u] = h[(size_t)sj[u] * 64 + lane];
                }
#pragma unroll
                for (int u = 0; u < 8; ++u)
                    acc = fmaf(exj[u], hv[u], acc);
            }
        }
        float o = (re > rs) ? (acc / ssum + b) : b;
        if (do_relu) o = fmaxf(o, 0.f);
        out[(size_t)v * 64 + lane] = o;
    }
}

extern "C" void kernel_launch(void* const* d_in, const int* in_sizes, int n_in,
                              void* d_out, int out_size, void* d_ws, size_t ws_size,
                              hipStream_t stream) {
    (void)n_in; (void)out_size; (void)ws_size;
    const float* features = (const float*)d_in[0];
    // d_in[1] = edge_weights, unused by the reference forward
    const int*   src = (const int*)d_in[2];
    const int*   dst = (const int*)d_in[3];
    const float* W1  = (const float*)d_in[4];
    const float* al1 = (const float*)d_in[5];
    const float* ar1 = (const float*)d_in[6];
    const float* b1  = (const float*)d_in[7];
    const float* W2  = (const float*)d_in[8];
    const float* al2 = (const float*)d_in[9];
    const float* ar2 = (const float*)d_in[10];
    const float* b2  = (const float*)d_in[11];

    const int n = in_sizes[0] / 128;   // 100000
    const int e = in_sizes[2];         // 1600000
    float* out = (float*)d_out;

    char* p = (char*)d_ws;
    auto alloc = [&](size_t bytes) -> char* {
        char* q = p;
        p += (bytes + 255) & ~(size_t)255;
        return q;
    };
    int*   row_off = (int*)alloc((size_t)(n + 1) * 4);
    int*   csr_src = (int*)alloc((size_t)e * 4);
    float* h       = (float*)alloc((size_t)n * 64 * 4);
    float* hr      = (float*)alloc((size_t)n * 64 * 4);
    float* el      = (float*)alloc((size_t)n * 4);
    float* er      = (float*)alloc((size_t)n * 4);
    int*   bkt_cnt = (int*)alloc(256 * 4);
    int*   bbase   = (int*)alloc(257 * 4);
    int*   gcur    = (int*)alloc(256 * 4);
    unsigned short* w1h = (unsigned short*)alloc(4 * 4 * 64 * 8 * 2);
    unsigned short* w1l = (unsigned short*)alloc(4 * 4 * 64 * 8 * 2);
    unsigned short* w2h = (unsigned short*)alloc(2 * 4 * 64 * 8 * 2);
    unsigned short* w2l = (unsigned short*)alloc(2 * 4 * 64 * 8 * 2);
    // part (e int2 = 12.8MB) aliases hr (25.6MB): consumed by finesort2 before
    // agg1 produces hr.
    int2*  part    = (int2*)hr;

    const int nbkt = (n + BKT_SIZE - 1) >> BKT_SHIFT;   // 196

    // W decomposition (tiny, once per launch)
    wprep_kernel<<<4, 256, 0, stream>>>(W1, w1h, w1l, 128);
    wprep_kernel<<<2, 256, 0, stream>>>(W2, w2h, w2l, 64);

    // CSR by dst (shared by both layers)
    hipMemsetAsync(bkt_cnt, 0, 256 * 4, stream);
    bucket_hist<<<1024, 256, 0, stream>>>(dst, e, bkt_cnt, nbkt);
    bkt_scan<<<1, 256, 0, stream>>>(bkt_cnt, bbase, gcur, nbkt, e);
    partition_kernel<<<(e + 256 * P1_EPT - 1) / (256 * P1_EPT), 256, 0, stream>>>(
        src, dst, e, gcur, part, nbkt);
    finesort2<<<nbkt, 256, 0, stream>>>(part, bbase, row_off, csr_src, n, e);

    // layer 1
    gemm_mfma_kernel<4><<<512, 256, 0, stream>>>(features, w1h, w1l, al1, ar1, h, el, er, n);
    agg_kernel<<<2048, 256, 0, stream>>>(row_off, csr_src, h, el, er, b1, hr, n, 1);

    // layer 2
    gemm_mfma_kernel<2><<<512, 256, 0, stream>>>(hr, w2h, w2l, al2, ar2, h, el, er, n);
    agg_kernel<<<2048, 256, 0, stream>>>(row_off, csr_src, h, el, er, b2, out, n, 0);
}

// Round 7
// 299.451 us; speedup vs baseline: 3.6104x; 1.1133x over previous
//
#include <hip/hip_runtime.h>
#include <hip/hip_fp16.h>

#define NEG_SLOPE 0.2f
#define BKT_SHIFT 9
#define BKT_SIZE (1 << BKT_SHIFT)
#define P1_EPT 16   // edges per thread in partition pass

typedef __attribute__((ext_vector_type(8))) short short8;
typedef __attribute__((ext_vector_type(4))) float float4v;

__device__ inline float readlane_f(float v, int l) {
    return __int_as_float(__builtin_amdgcn_readlane(__float_as_int(v), l));
}
__device__ inline int readlane_i(int v, int l) {
    return __builtin_amdgcn_readlane(v, l);
}
__device__ inline int rfl_i(int v) { return __builtin_amdgcn_readfirstlane(v); }

// round-to-nearest-even fp32 -> bf16
__device__ inline unsigned short f2bf(float f) {
    unsigned u = __float_as_uint(f);
    unsigned r = u + 0x7FFFu + ((u >> 16) & 1u);
    return (unsigned short)(r >> 16);
}
__device__ inline float bf2f(unsigned short b) {
    return __uint_as_float(((unsigned)b) << 16);
}

// ---------------- CSR build ----------------

__global__ __launch_bounds__(256) void bucket_hist(const int* __restrict__ dst, int e,
                                                   int* __restrict__ bkt_cnt, int nbkt) {
    __shared__ int lc[256];
    int t = threadIdx.x;
    lc[t] = 0;
    __syncthreads();
    int stride = gridDim.x * blockDim.x;
    for (int i = blockIdx.x * blockDim.x + t; i < e; i += stride)
        atomicAdd(&lc[dst[i] >> BKT_SHIFT], 1);
    __syncthreads();
    if (t < nbkt && lc[t]) atomicAdd(&bkt_cnt[t], lc[t]);
}

// 1 block x 256: exclusive scan of bucket counts -> bbase[0..nbkt], gcur.
__global__ void bkt_scan(const int* __restrict__ bkt_cnt, int* __restrict__ bbase,
                         int* __restrict__ gcur, int nbkt, int e_total) {
    __shared__ int tmp[256];
    int t = threadIdx.x;
    int v = (t < nbkt) ? bkt_cnt[t] : 0;
    tmp[t] = v;
    __syncthreads();
    for (int o = 1; o < 256; o <<= 1) {
        int x = tmp[t];
        int y = (t >= o) ? tmp[t - o] : 0;
        __syncthreads();
        tmp[t] = x + y;
        __syncthreads();
    }
    if (t < nbkt) {
        int ex = tmp[t] - v;
        bbase[t] = ex;
        gcur[t] = ex;
    }
    if (t == 0) bbase[nbkt] = e_total;
}

// Per-wave LDS counters (4 x 256) cut cross-wave same-bin atomic contention.
__global__ __launch_bounds__(256) void partition_kernel(
        const int* __restrict__ src, const int* __restrict__ dst, int e,
        int* __restrict__ gcur, int2* __restrict__ part, int nbkt) {
    __shared__ int cnt[4][256];
    __shared__ int base_l[4][256];
    int t = threadIdx.x;
    int wv = t >> 6;
    int cb = blockIdx.x * (256 * P1_EPT);
    for (int i = t; i < 4 * 256; i += 256) ((int*)cnt)[i] = 0;
    __syncthreads();
    int sr[P1_EPT], ds[P1_EPT], rk[P1_EPT];
#pragma unroll
    for (int i = 0; i < P1_EPT; ++i) {
        int eid = cb + t + i * 256;
        if (eid < e) {
            sr[i] = src[eid];
            ds[i] = dst[eid];
            rk[i] = atomicAdd(&cnt[wv][ds[i] >> BKT_SHIFT], 1);
        } else {
            rk[i] = -1;
        }
    }
    __syncthreads();
    if (t < nbkt) {
        int c0 = cnt[0][t], c1 = cnt[1][t], c2 = cnt[2][t], c3 = cnt[3][t];
        int tot = c0 + c1 + c2 + c3;
        int gb = (tot > 0) ? atomicAdd(&gcur[t], tot) : 0;
        base_l[0][t] = gb;
        base_l[1][t] = gb + c0;
        base_l[2][t] = gb + c0 + c1;
        base_l[3][t] = gb + c0 + c1 + c2;
    }
    __syncthreads();
#pragma unroll
    for (int i = 0; i < P1_EPT; ++i) {
        if (rk[i] >= 0) {
            int b = ds[i] >> BKT_SHIFT;
            part[base_l[wv][b] + rk[i]] = make_int2(sr[i], ds[i]);
        }
    }
}

// Per bucket (512 dst nodes): count per-dst in LDS, block-scan 512, write this
// bucket's row_off slice (coalesced), then scatter within the bucket's
// csr window (~tens of KB -> L2-resident, full-line writebacks only).
__global__ __launch_bounds__(256) void finesort2(
        const int2* __restrict__ part, const int* __restrict__ bbase,
        int* __restrict__ row_off, int* __restrict__ csr_src, int n, int e_total) {
    __shared__ int cnt[BKT_SIZE];
    __shared__ int cur[BKT_SIZE];
    __shared__ int tmp[256];
    int b = blockIdx.x, t = threadIdx.x;
    int d0 = b << BKT_SHIFT;
    int dlim = min(d0 + BKT_SIZE, n);
    int nloc = dlim - d0;
    for (int i = t; i < BKT_SIZE; i += 256) cnt[i] = 0;
    __syncthreads();
    int base = bbase[b], bend = bbase[b + 1];
    for (int i = base + t; i < bend; i += 256)
        atomicAdd(&cnt[part[i].y - d0], 1);
    __syncthreads();
    int c0 = cnt[2 * t], c1 = cnt[2 * t + 1];
    int s = c0 + c1;
    tmp[t] = s;
    __syncthreads();
    for (int o = 1; o < 256; o <<= 1) {
        int x = tmp[t];
        int y = (t >= o) ? tmp[t - o] : 0;
        __syncthreads();
        tmp[t] = x + y;
        __syncthreads();
    }
    int excl = tmp[t] - s;
    cur[2 * t] = base + excl;
    cur[2 * t + 1] = base + excl + c0;
    __syncthreads();
    for (int i = t; i < nloc; i += 256) row_off[d0 + i] = cur[i];
    if (dlim == n && t == 0) row_off[n] = e_total;
    __syncthreads();
    for (int i = base + t; i < bend; i += 256) {
        int2 p = part[i];
        int pos = atomicAdd(&cur[p.y - d0], 1);
        csr_src[pos] = p.x;
    }
}

// ---------------- W decomposition into MFMA frag order ----------------
__global__ void wprep_kernel(const float* __restrict__ W, unsigned short* __restrict__ wh,
                             unsigned short* __restrict__ wl, int K) {
    int idx = blockIdx.x * blockDim.x + threadIdx.x;   // (kt*4+fb)*64 + lane
    int KT = K / 32;
    if (idx >= KT * 4 * 64) return;
    int lane = idx & 63;
    int fbkt = idx >> 6;
    int fb = fbkt & 3, kt = fbkt >> 2;
    int q = lane >> 4, c = lane & 15;
    for (int j = 0; j < 8; ++j) {
        float w = W[(kt * 32 + q * 8 + j) * 64 + fb * 16 + c];
        unsigned short hi = f2bf(w);
        wh[idx * 8 + j] = hi;
        wl[idx * 8 + j] = f2bf(w - bf2f(hi));
    }
}

// ---------------- MFMA GEMM + attention dots ----------------
// h[N,64] = x[N,K] @ W[K,64] via v_mfma_f32_16x16x32_bf16, bf16x3 split.
// Epilogue writes h16 (fp16, 128B/row = one cache line) -- the only consumer
// of h is the agg gather; el/er come from the fp32 accumulators here.
template <int KT>
__global__ __launch_bounds__(256) void gemm_mfma_kernel(
        const float* __restrict__ x, const unsigned short* __restrict__ wh,
        const unsigned short* __restrict__ wl,
        const float* __restrict__ al, const float* __restrict__ ar,
        __half* __restrict__ h16, float* __restrict__ el,
        float* __restrict__ er, int n) {
    constexpr int K = KT * 32;
    constexpr int WFRAG = KT * 4 * 64 * 8;   // shorts
    __shared__ unsigned short Wh[WFRAG];
    __shared__ unsigned short Wl[WFRAG];
    for (int i = threadIdx.x; i < WFRAG / 8; i += 256) {
        ((float4*)Wh)[i] = ((const float4*)wh)[i];
        ((float4*)Wl)[i] = ((const float4*)wl)[i];
    }
    __syncthreads();

    int lane = threadIdx.x & 63;
    int q = lane >> 4, c = lane & 15;
    int wave = (int)((blockIdx.x * blockDim.x + threadIdx.x) >> 6);
    int nwaves = (gridDim.x * blockDim.x) >> 6;
    int ntiles = (n + 15) >> 4;

    float alv[4], arv[4];
#pragma unroll
    for (int fb = 0; fb < 4; ++fb) {
        alv[fb] = al[fb * 16 + c];
        arv[fb] = ar[fb * 16 + c];
    }

    for (int t = wave; t < ntiles; t += nwaves) {
        int v0 = t * 16;
        int row = min(v0 + c, n - 1);
        const float* xr = x + (size_t)row * K + q * 8;

        short8 Ah[KT], Al[KT];
#pragma unroll
        for (int kt = 0; kt < KT; ++kt) {
            float xv[8];
            *(float4*)&xv[0] = *(const float4*)(xr + kt * 32);
            *(float4*)&xv[4] = *(const float4*)(xr + kt * 32 + 4);
#pragma unroll
            for (int j = 0; j < 8; ++j) {
                unsigned short hi = f2bf(xv[j]);
                Ah[kt][j] = (short)hi;
                Al[kt][j] = (short)f2bf(xv[j] - bf2f(hi));
            }
        }

        float4v acc[4];
#pragma unroll
        for (int fb = 0; fb < 4; ++fb) acc[fb] = (float4v)0.f;

#pragma unroll
        for (int kt = 0; kt < KT; ++kt) {
#pragma unroll
            for (int fb = 0; fb < 4; ++fb) {
                short8 bh = *(const short8*)&Wh[((kt * 4 + fb) * 64 + lane) * 8];
                short8 bl = *(const short8*)&Wl[((kt * 4 + fb) * 64 + lane) * 8];
                acc[fb] = __builtin_amdgcn_mfma_f32_16x16x32_bf16(Ah[kt], bh, acc[fb], 0, 0, 0);
                acc[fb] = __builtin_amdgcn_mfma_f32_16x16x32_bf16(Al[kt], bh, acc[fb], 0, 0, 0);
                acc[fb] = __builtin_amdgcn_mfma_f32_16x16x32_bf16(Ah[kt], bl, acc[fb], 0, 0, 0);
            }
        }

#pragma unroll
        for (int r = 0; r < 4; ++r) {
            int v = v0 + q * 4 + r;
            float pl = 0.f, pr = 0.f;
            bool ok = (v < n);
#pragma unroll
            for (int fb = 0; fb < 4; ++fb) {
                float hv = acc[fb][r];
                if (ok) h16[(size_t)v * 64 + fb * 16 + c] = __float2half(hv);
                pl = fmaf(hv, alv[fb], pl);
                pr = fmaf(hv, arv[fb], pr);
            }
#pragma unroll
            for (int off = 8; off > 0; off >>= 1) {
                pl += __shfl_xor(pl, off);
                pr += __shfl_xor(pr, off);
            }
            if (ok && c == 0) { el[v] = pl; er[v] = pr; }
        }
    }
}

// ---------------- softmax-aggregate ----------------
// Gathers fp16 h rows (128B = one line per edge), accumulates fp32.
__global__ __launch_bounds__(256) void agg_kernel(
        const int* __restrict__ row_off, const int* __restrict__ csr_src,
        const __half* __restrict__ h16, const float* __restrict__ el,
        const float* __restrict__ er, const float* __restrict__ bias,
        float* __restrict__ out, int n, int do_relu) {
    int lane = threadIdx.x & 63;
    int gwave = rfl_i((int)((blockIdx.x * blockDim.x + threadIdx.x) >> 6));
    int nwaves = (gridDim.x * blockDim.x) >> 6;
    float b = bias[lane];
    for (int v = gwave; v < n; v += nwaves) {
        int rs = rfl_i(row_off[v]), re = rfl_i(row_off[v + 1]);
        float er_v = er[v];
        float acc = 0.f, ssum = 0.f;
        for (int base = rs; base < re; base += 64) {
            int cnt = min(64, re - base);
            int s_e = 0;
            float ex = 0.f;
            if (lane < cnt) {
                s_e = csr_src[base + lane];
                float ev = el[s_e] + er_v;
                ev = (ev >= 0.f) ? ev : NEG_SLOPE * ev;
                ex = __expf(ev);
            }
            float cs = ex;
#pragma unroll
            for (int off = 32; off > 0; off >>= 1) cs += __shfl_xor(cs, off);
            ssum += cs;
            int cnt8 = (cnt + 7) & ~7;
            for (int j = 0; j < cnt8; j += 8) {
                int sj[8];
                float exj[8];
                __half hv[8];
#pragma unroll
                for (int u = 0; u < 8; ++u) {
                    sj[u] = readlane_i(s_e, j + u);
                    exj[u] = readlane_f(ex, j + u);
                    hv[u] = h16[(size_t)sj[u] * 64 + lane];
                }
#pragma unroll
                for (int u = 0; u < 8; ++u)
                    acc = fmaf(exj[u], __half2float(hv[u]), acc);
            }
        }
        float o = (re > rs) ? (acc / ssum + b) : b;
        if (do_relu) o = fmaxf(o, 0.f);
        out[(size_t)v * 64 + lane] = o;
    }
}

extern "C" void kernel_launch(void* const* d_in, const int* in_sizes, int n_in,
                              void* d_out, int out_size, void* d_ws, size_t ws_size,
                              hipStream_t stream) {
    (void)n_in; (void)out_size; (void)ws_size;
    const float* features = (const float*)d_in[0];
    // d_in[1] = edge_weights, unused by the reference forward
    const int*   src = (const int*)d_in[2];
    const int*   dst = (const int*)d_in[3];
    const float* W1  = (const float*)d_in[4];
    const float* al1 = (const float*)d_in[5];
    const float* ar1 = (const float*)d_in[6];
    const float* b1  = (const float*)d_in[7];
    const float* W2  = (const float*)d_in[8];
    const float* al2 = (const float*)d_in[9];
    const float* ar2 = (const float*)d_in[10];
    const float* b2  = (const float*)d_in[11];

    const int n = in_sizes[0] / 128;   // 100000
    const int e = in_sizes[2];         // 1600000
    float* out = (float*)d_out;

    char* p = (char*)d_ws;
    auto alloc = [&](size_t bytes) -> char* {
        char* q = p;
        p += (bytes + 255) & ~(size_t)255;
        return q;
    };
    int*    row_off = (int*)alloc((size_t)(n + 1) * 4);
    int*    csr_src = (int*)alloc((size_t)e * 4);
    __half* h16     = (__half*)alloc((size_t)n * 64 * 2);
    float*  hr      = (float*)alloc((size_t)n * 64 * 4);
    float*  el      = (float*)alloc((size_t)n * 4);
    float*  er      = (float*)alloc((size_t)n * 4);
    int*    bkt_cnt = (int*)alloc(256 * 4);
    int*    bbase   = (int*)alloc(257 * 4);
    int*    gcur    = (int*)alloc(256 * 4);
    unsigned short* w1h = (unsigned short*)alloc(4 * 4 * 64 * 8 * 2);
    unsigned short* w1l = (unsigned short*)alloc(4 * 4 * 64 * 8 * 2);
    unsigned short* w2h = (unsigned short*)alloc(2 * 4 * 64 * 8 * 2);
    unsigned short* w2l = (unsigned short*)alloc(2 * 4 * 64 * 8 * 2);
    // part (e int2 = 12.8MB) aliases hr (25.6MB): consumed by finesort2 before
    // agg1 produces hr.
    int2*   part    = (int2*)hr;

    const int nbkt = (n + BKT_SIZE - 1) >> BKT_SHIFT;   // 196

    // W decomposition (tiny, once per launch)
    wprep_kernel<<<4, 256, 0, stream>>>(W1, w1h, w1l, 128);
    wprep_kernel<<<2, 256, 0, stream>>>(W2, w2h, w2l, 64);

    // CSR by dst (shared by both layers)
    hipMemsetAsync(bkt_cnt, 0, 256 * 4, stream);
    bucket_hist<<<1024, 256, 0, stream>>>(dst, e, bkt_cnt, nbkt);
    bkt_scan<<<1, 256, 0, stream>>>(bkt_cnt, bbase, gcur, nbkt, e);
    partition_kernel<<<(e + 256 * P1_EPT - 1) / (256 * P1_EPT), 256, 0, stream>>>(
        src, dst, e, gcur, part, nbkt);
    finesort2<<<nbkt, 256, 0, stream>>>(part, bbase, row_off, csr_src, n, e);

    // layer 1
    gemm_mfma_kernel<4><<<512, 256, 0, stream>>>(features, w1h, w1l, al1, ar1, h16, el, er, n);
    agg_kernel<<<2048, 256, 0, stream>>>(row_off, csr_src, h16, el, er, b1, hr, n, 1);

    // layer 2
    gemm_mfma_kernel<2><<<512, 256, 0, stream>>>(hr, w2h, w2l, al2, ar2, h16, el, er, n);
    agg_kernel<<<2048, 256, 0, stream>>>(row_off, csr_src, h16, el, er, b2, out, n, 0);
}

// Round 8
// 281.472 us; speedup vs baseline: 3.8410x; 1.0639x over previous
//
#include <hip/hip_runtime.h>
#include <hip/hip_fp16.h>

#define NEG_SLOPE 0.2f
#define BKT_SHIFT 9
#define BKT_SIZE (1 << BKT_SHIFT)
#define P1_EPT 16   // edges per thread in partition pass

typedef __attribute__((ext_vector_type(8))) short short8;
typedef __attribute__((ext_vector_type(4))) float float4v;

__device__ inline float readlane_f(float v, int l) {
    return __int_as_float(__builtin_amdgcn_readlane(__float_as_int(v), l));
}
__device__ inline int rfl_i(int v) { return __builtin_amdgcn_readfirstlane(v); }

// round-to-nearest-even fp32 -> bf16
__device__ inline unsigned short f2bf(float f) {
    unsigned u = __float_as_uint(f);
    unsigned r = u + 0x7FFFu + ((u >> 16) & 1u);
    return (unsigned short)(r >> 16);
}
__device__ inline float bf2f(unsigned short b) {
    return __uint_as_float(((unsigned)b) << 16);
}

// ---------------- CSR build ----------------

__global__ __launch_bounds__(256) void bucket_hist(const int* __restrict__ dst, int e,
                                                   int* __restrict__ bkt_cnt, int nbkt) {
    __shared__ int lc[256];
    int t = threadIdx.x;
    lc[t] = 0;
    __syncthreads();
    int stride = gridDim.x * blockDim.x;
    for (int i = blockIdx.x * blockDim.x + t; i < e; i += stride)
        atomicAdd(&lc[dst[i] >> BKT_SHIFT], 1);
    __syncthreads();
    if (t < nbkt && lc[t]) atomicAdd(&bkt_cnt[t], lc[t]);
}

// 1 block x 256: exclusive scan of bucket counts -> bbase[0..nbkt], gcur.
__global__ void bkt_scan(const int* __restrict__ bkt_cnt, int* __restrict__ bbase,
                         int* __restrict__ gcur, int nbkt, int e_total) {
    __shared__ int tmp[256];
    int t = threadIdx.x;
    int v = (t < nbkt) ? bkt_cnt[t] : 0;
    tmp[t] = v;
    __syncthreads();
    for (int o = 1; o < 256; o <<= 1) {
        int x = tmp[t];
        int y = (t >= o) ? tmp[t - o] : 0;
        __syncthreads();
        tmp[t] = x + y;
        __syncthreads();
    }
    if (t < nbkt) {
        int ex = tmp[t] - v;
        bbase[t] = ex;
        gcur[t] = ex;
    }
    if (t == 0) bbase[nbkt] = e_total;
}

// Per-wave LDS counters (4 x 256) cut cross-wave same-bin atomic contention.
// Record packed to 4B: src<<9 | (dst & 511)  (src<2^17, local dst 9 bits).
__global__ __launch_bounds__(256) void partition_kernel(
        const int* __restrict__ src, const int* __restrict__ dst, int e,
        int* __restrict__ gcur, int* __restrict__ part, int nbkt) {
    __shared__ int cnt[4][256];
    __shared__ int base_l[4][256];
    int t = threadIdx.x;
    int wv = t >> 6;
    int cb = blockIdx.x * (256 * P1_EPT);
    for (int i = t; i < 4 * 256; i += 256) ((int*)cnt)[i] = 0;
    __syncthreads();
    int sr[P1_EPT], ds[P1_EPT], rk[P1_EPT];
#pragma unroll
    for (int i = 0; i < P1_EPT; ++i) {
        int eid = cb + t + i * 256;
        if (eid < e) {
            sr[i] = src[eid];
            ds[i] = dst[eid];
            rk[i] = atomicAdd(&cnt[wv][ds[i] >> BKT_SHIFT], 1);
        } else {
            rk[i] = -1;
        }
    }
    __syncthreads();
    if (t < nbkt) {
        int c0 = cnt[0][t], c1 = cnt[1][t], c2 = cnt[2][t], c3 = cnt[3][t];
        int tot = c0 + c1 + c2 + c3;
        int gb = (tot > 0) ? atomicAdd(&gcur[t], tot) : 0;
        base_l[0][t] = gb;
        base_l[1][t] = gb + c0;
        base_l[2][t] = gb + c0 + c1;
        base_l[3][t] = gb + c0 + c1 + c2;
    }
    __syncthreads();
#pragma unroll
    for (int i = 0; i < P1_EPT; ++i) {
        if (rk[i] >= 0) {
            int b = ds[i] >> BKT_SHIFT;
            part[base_l[wv][b] + rk[i]] = (sr[i] << BKT_SHIFT) | (ds[i] & (BKT_SIZE - 1));
        }
    }
}

// Per bucket (512 dst nodes): count per-dst in LDS, block-scan 512, write this
// bucket's row_off slice (coalesced), then scatter within the bucket's
// csr window (~tens of KB -> L2-resident, full-line writebacks only).
__global__ __launch_bounds__(256) void finesort2(
        const int* __restrict__ part, const int* __restrict__ bbase,
        int* __restrict__ row_off, int* __restrict__ csr_src, int n, int e_total) {
    __shared__ int cnt[BKT_SIZE];
    __shared__ int cur[BKT_SIZE];
    __shared__ int tmp[256];
    int b = blockIdx.x, t = threadIdx.x;
    int d0 = b << BKT_SHIFT;
    int dlim = min(d0 + BKT_SIZE, n);
    int nloc = dlim - d0;
    for (int i = t; i < BKT_SIZE; i += 256) cnt[i] = 0;
    __syncthreads();
    int base = bbase[b], bend = bbase[b + 1];
    for (int i = base + t; i < bend; i += 256)
        atomicAdd(&cnt[part[i] & (BKT_SIZE - 1)], 1);
    __syncthreads();
    int c0 = cnt[2 * t], c1 = cnt[2 * t + 1];
    int s = c0 + c1;
    tmp[t] = s;
    __syncthreads();
    for (int o = 1; o < 256; o <<= 1) {
        int x = tmp[t];
        int y = (t >= o) ? tmp[t - o] : 0;
        __syncthreads();
        tmp[t] = x + y;
        __syncthreads();
    }
    int excl = tmp[t] - s;
    cur[2 * t] = base + excl;
    cur[2 * t + 1] = base + excl + c0;
    __syncthreads();
    for (int i = t; i < nloc; i += 256) row_off[d0 + i] = cur[i];
    if (dlim == n && t == 0) row_off[n] = e_total;
    __syncthreads();
    for (int i = base + t; i < bend; i += 256) {
        int pk = part[i];
        int pos = atomicAdd(&cur[pk & (BKT_SIZE - 1)], 1);
        csr_src[pos] = ((unsigned)pk) >> BKT_SHIFT;
    }
}

// ---------------- W decomposition into MFMA frag order ----------------
__global__ void wprep_kernel(const float* __restrict__ W, unsigned short* __restrict__ wh,
                             unsigned short* __restrict__ wl, int K) {
    int idx = blockIdx.x * blockDim.x + threadIdx.x;   // (kt*4+fb)*64 + lane
    int KT = K / 32;
    if (idx >= KT * 4 * 64) return;
    int lane = idx & 63;
    int fbkt = idx >> 6;
    int fb = fbkt & 3, kt = fbkt >> 2;
    int q = lane >> 4, c = lane & 15;
    for (int j = 0; j < 8; ++j) {
        float w = W[(kt * 32 + q * 8 + j) * 64 + fb * 16 + c];
        unsigned short hi = f2bf(w);
        wh[idx * 8 + j] = hi;
        wl[idx * 8 + j] = f2bf(w - bf2f(hi));
    }
}

// ---------------- MFMA GEMM + attention dots ----------------
template <int KT>
__global__ __launch_bounds__(256) void gemm_mfma_kernel(
        const float* __restrict__ x, const unsigned short* __restrict__ wh,
        const unsigned short* __restrict__ wl,
        const float* __restrict__ al, const float* __restrict__ ar,
        __half* __restrict__ h16, float* __restrict__ el,
        float* __restrict__ er, int n) {
    constexpr int K = KT * 32;
    constexpr int WFRAG = KT * 4 * 64 * 8;   // shorts
    __shared__ unsigned short Wh[WFRAG];
    __shared__ unsigned short Wl[WFRAG];
    for (int i = threadIdx.x; i < WFRAG / 8; i += 256) {
        ((float4*)Wh)[i] = ((const float4*)wh)[i];
        ((float4*)Wl)[i] = ((const float4*)wl)[i];
    }
    __syncthreads();

    int lane = threadIdx.x & 63;
    int q = lane >> 4, c = lane & 15;
    int wave = (int)((blockIdx.x * blockDim.x + threadIdx.x) >> 6);
    int nwaves = (gridDim.x * blockDim.x) >> 6;
    int ntiles = (n + 15) >> 4;

    float alv[4], arv[4];
#pragma unroll
    for (int fb = 0; fb < 4; ++fb) {
        alv[fb] = al[fb * 16 + c];
        arv[fb] = ar[fb * 16 + c];
    }

    for (int t = wave; t < ntiles; t += nwaves) {
        int v0 = t * 16;
        int row = min(v0 + c, n - 1);
        const float* xr = x + (size_t)row * K + q * 8;

        short8 Ah[KT], Al[KT];
#pragma unroll
        for (int kt = 0; kt < KT; ++kt) {
            float xv[8];
            *(float4*)&xv[0] = *(const float4*)(xr + kt * 32);
            *(float4*)&xv[4] = *(const float4*)(xr + kt * 32 + 4);
#pragma unroll
            for (int j = 0; j < 8; ++j) {
                unsigned short hi = f2bf(xv[j]);
                Ah[kt][j] = (short)hi;
                Al[kt][j] = (short)f2bf(xv[j] - bf2f(hi));
            }
        }

        float4v acc[4];
#pragma unroll
        for (int fb = 0; fb < 4; ++fb) acc[fb] = (float4v)0.f;

#pragma unroll
        for (int kt = 0; kt < KT; ++kt) {
#pragma unroll
            for (int fb = 0; fb < 4; ++fb) {
                short8 bh = *(const short8*)&Wh[((kt * 4 + fb) * 64 + lane) * 8];
                short8 bl = *(const short8*)&Wl[((kt * 4 + fb) * 64 + lane) * 8];
                acc[fb] = __builtin_amdgcn_mfma_f32_16x16x32_bf16(Ah[kt], bh, acc[fb], 0, 0, 0);
                acc[fb] = __builtin_amdgcn_mfma_f32_16x16x32_bf16(Al[kt], bh, acc[fb], 0, 0, 0);
                acc[fb] = __builtin_amdgcn_mfma_f32_16x16x32_bf16(Ah[kt], bl, acc[fb], 0, 0, 0);
            }
        }

#pragma unroll
        for (int r = 0; r < 4; ++r) {
            int v = v0 + q * 4 + r;
            float pl = 0.f, pr = 0.f;
            bool ok = (v < n);
#pragma unroll
            for (int fb = 0; fb < 4; ++fb) {
                float hv = acc[fb][r];
                if (ok) h16[(size_t)v * 64 + fb * 16 + c] = __float2half(hv);
                pl = fmaf(hv, alv[fb], pl);
                pr = fmaf(hv, arv[fb], pr);
            }
#pragma unroll
            for (int off = 8; off > 0; off >>= 1) {
                pl += __shfl_xor(pl, off);
                pr += __shfl_xor(pr, off);
            }
            if (ok && c == 0) { el[v] = pl; er[v] = pr; }
        }
    }
}

// ---------------- softmax-aggregate ----------------
// 4 edges processed per wave step: 16-lane group g owns edge j+g, each lane
// loads uint2 (4 fp16 features) -> one VMEM inst gathers 4 edges (4 random
// 128B lines) instead of 4 insts. Edge scalar/index broadcast to the group
// via ds_bpermute (__shfl with per-lane index). Epilogue xor-reduces over
// lane bits 4-5; lanes 0-15 write float4 (256B coalesced row).
__global__ __launch_bounds__(256) void agg_kernel(
        const int* __restrict__ row_off, const int* __restrict__ csr_src,
        const __half* __restrict__ h16, const float* __restrict__ el,
        const float* __restrict__ er, const float* __restrict__ bias,
        float* __restrict__ out, int n, int do_relu) {
    int lane = threadIdx.x & 63;
    int grp = lane >> 4;      // 0..3: edge slot within a 4-edge step
    int c = lane & 15;        // feature quad: features 4c..4c+3
    int gwave = rfl_i((int)((blockIdx.x * blockDim.x + threadIdx.x) >> 6));
    int nwaves = (gridDim.x * blockDim.x) >> 6;
    float4 b4 = ((const float4*)bias)[c];
    for (int v = gwave; v < n; v += nwaves) {
        int rs = rfl_i(row_off[v]), re = rfl_i(row_off[v + 1]);
        float er_v = er[v];
        float a0 = 0.f, a1 = 0.f, a2 = 0.f, a3 = 0.f, ssum = 0.f;
        for (int base = rs; base < re; base += 64) {
            int cnt = min(64, re - base);
            int s_e = 0;
            float ex = 0.f;
            if (lane < cnt) {
                s_e = csr_src[base + lane];
                float ev = el[s_e] + er_v;
                ev = (ev >= 0.f) ? ev : NEG_SLOPE * ev;
                ex = __expf(ev);
            }
            float cs = ex;
#pragma unroll
            for (int off = 32; off > 0; off >>= 1) cs += __shfl_xor(cs, off);
            ssum += cs;
            int cnt16 = (cnt + 15) & ~15;
            for (int j = 0; j < cnt16; j += 16) {
                int sj[4];
                float exj[4];
                uint2 hv[4];
#pragma unroll
                for (int u = 0; u < 4; ++u) {
                    int idx = j + 4 * u + grp;
                    sj[u] = __shfl(s_e, idx);
                    exj[u] = __shfl(ex, idx);
                    hv[u] = *((const uint2*)(h16 + (size_t)sj[u] * 64) + c);
                }
#pragma unroll
                for (int u = 0; u < 4; ++u) {
                    float2 f01 = __half22float2(*(__half2*)&hv[u].x);
                    float2 f23 = __half22float2(*(__half2*)&hv[u].y);
                    a0 = fmaf(exj[u], f01.x, a0);
                    a1 = fmaf(exj[u], f01.y, a1);
                    a2 = fmaf(exj[u], f23.x, a2);
                    a3 = fmaf(exj[u], f23.y, a3);
                }
            }
        }
        // combine the 4 edge-groups: reduce over lane bits 4,5
#pragma unroll
        for (int off = 16; off < 64; off <<= 1) {
            a0 += __shfl_xor(a0, off);
            a1 += __shfl_xor(a1, off);
            a2 += __shfl_xor(a2, off);
            a3 += __shfl_xor(a3, off);
        }
        if (lane < 16) {
            float4 o;
            if (re > rs) {
                float inv = 1.0f / ssum;
                o.x = fmaf(a0, inv, b4.x);
                o.y = fmaf(a1, inv, b4.y);
                o.z = fmaf(a2, inv, b4.z);
                o.w = fmaf(a3, inv, b4.w);
            } else {
                o = b4;
            }
            if (do_relu) {
                o.x = fmaxf(o.x, 0.f);
                o.y = fmaxf(o.y, 0.f);
                o.z = fmaxf(o.z, 0.f);
                o.w = fmaxf(o.w, 0.f);
            }
            ((float4*)(out + (size_t)v * 64))[c] = o;
        }
    }
}

extern "C" void kernel_launch(void* const* d_in, const int* in_sizes, int n_in,
                              void* d_out, int out_size, void* d_ws, size_t ws_size,
                              hipStream_t stream) {
    (void)n_in; (void)out_size; (void)ws_size;
    const float* features = (const float*)d_in[0];
    // d_in[1] = edge_weights, unused by the reference forward
    const int*   src = (const int*)d_in[2];
    const int*   dst = (const int*)d_in[3];
    const float* W1  = (const float*)d_in[4];
    const float* al1 = (const float*)d_in[5];
    const float* ar1 = (const float*)d_in[6];
    const float* b1  = (const float*)d_in[7];
    const float* W2  = (const float*)d_in[8];
    const float* al2 = (const float*)d_in[9];
    const float* ar2 = (const float*)d_in[10];
    const float* b2  = (const float*)d_in[11];

    const int n = in_sizes[0] / 128;   // 100000
    const int e = in_sizes[2];         // 1600000
    float* out = (float*)d_out;

    char* p = (char*)d_ws;
    auto alloc = [&](size_t bytes) -> char* {
        char* q = p;
        p += (bytes + 255) & ~(size_t)255;
        return q;
    };
    int*    row_off = (int*)alloc((size_t)(n + 1) * 4);
    int*    csr_src = (int*)alloc((size_t)e * 4);
    __half* h16     = (__half*)alloc((size_t)n * 64 * 2);
    float*  hr      = (float*)alloc((size_t)n * 64 * 4);
    float*  el      = (float*)alloc((size_t)n * 4);
    float*  er      = (float*)alloc((size_t)n * 4);
    int*    bkt_cnt = (int*)alloc(256 * 4);
    int*    bbase   = (int*)alloc(257 * 4);
    int*    gcur    = (int*)alloc(256 * 4);
    unsigned short* w1h = (unsigned short*)alloc(4 * 4 * 64 * 8 * 2);
    unsigned short* w1l = (unsigned short*)alloc(4 * 4 * 64 * 8 * 2);
    unsigned short* w2h = (unsigned short*)alloc(2 * 4 * 64 * 8 * 2);
    unsigned short* w2l = (unsigned short*)alloc(2 * 4 * 64 * 8 * 2);
    // part (e int = 6.4MB) aliases hr (25.6MB): consumed by finesort2 before
    // agg1 produces hr.
    int*    part    = (int*)hr;

    const int nbkt = (n + BKT_SIZE - 1) >> BKT_SHIFT;   // 196

    // W decomposition (tiny, once per launch)
    wprep_kernel<<<4, 256, 0, stream>>>(W1, w1h, w1l, 128);
    wprep_kernel<<<2, 256, 0, stream>>>(W2, w2h, w2l, 64);

    // CSR by dst (shared by both layers)
    hipMemsetAsync(bkt_cnt, 0, 256 * 4, stream);
    bucket_hist<<<1024, 256, 0, stream>>>(dst, e, bkt_cnt, nbkt);
    bkt_scan<<<1, 256, 0, stream>>>(bkt_cnt, bbase, gcur, nbkt, e);
    partition_kernel<<<(e + 256 * P1_EPT - 1) / (256 * P1_EPT), 256, 0, stream>>>(
        src, dst, e, gcur, part, nbkt);
    finesort2<<<nbkt, 256, 0, stream>>>(part, bbase, row_off, csr_src, n, e);

    // layer 1
    gemm_mfma_kernel<4><<<512, 256, 0, stream>>>(features, w1h, w1l, al1, ar1, h16, el, er, n);
    agg_kernel<<<2048, 256, 0, stream>>>(row_off, csr_src, h16, el, er, b1, hr, n, 1);

    // layer 2
    gemm_mfma_kernel<2><<<512, 256, 0, stream>>>(hr, w2h, w2l, al2, ar2, h16, el, er, n);
    agg_kernel<<<2048, 256, 0, stream>>>(row_off, csr_src, h16, el, er, b2, out, n, 0);
}

// Round 9
// 251.934 us; speedup vs baseline: 4.2913x; 1.1172x over previous
//
#include <hip/hip_runtime.h>
#include <hip/hip_fp16.h>
#include <type_traits>

#define NEG_SLOPE 0.2f
#define BKT_SHIFT 8
#define BKT_SIZE (1 << BKT_SHIFT)     // 256 dst nodes per bucket
#define BKT_CAP 12288                 // arena slots/bucket (mean 4096; overflow ~impossible)
#define P1_EPT 16                     // edges per thread in partition pass

typedef __attribute__((ext_vector_type(8))) short short8;
typedef __attribute__((ext_vector_type(4))) float float4v;

__device__ inline int rfl_i(int v) { return __builtin_amdgcn_readfirstlane(v); }

// round-to-nearest-even fp32 -> bf16
__device__ inline unsigned short f2bf(float f) {
    unsigned u = __float_as_uint(f);
    unsigned r = u + 0x7FFFu + ((u >> 16) & 1u);
    return (unsigned short)(r >> 16);
}
__device__ inline float bf2f(unsigned short b) {
    return __uint_as_float(((unsigned)b) << 16);
}

// ---------------- CSR build (arena partition; no pre-histogram) ----------------

__global__ void init_cur(int* __restrict__ gcur, int nbkt) {
    int t = blockIdx.x * blockDim.x + threadIdx.x;
    if (t < nbkt) gcur[t] = t * BKT_CAP;
}

// Coarse partition into dst>>8 buckets, each bucket appending into its private
// arena [b*CAP, ...). Per-wave LDS counters; int4-vectorized edge loads.
// Record packed to 4B: src<<8 | (dst & 255)   (src < 2^17 -> 25 bits).
__global__ __launch_bounds__(256) void partition_kernel(
        const int* __restrict__ src, const int* __restrict__ dst, int e,
        int* __restrict__ gcur, int* __restrict__ part, int nbkt) {
    __shared__ int cnt[4][392];
    __shared__ int base_l[4][392];
    int t = threadIdx.x;
    int wv = t >> 6;
    int cb = blockIdx.x * (256 * P1_EPT);
    for (int i = t; i < 4 * 392; i += 256) ((int*)cnt)[i] = 0;
    __syncthreads();
    int sr[P1_EPT], ds[P1_EPT], rk[P1_EPT];
#pragma unroll
    for (int i4 = 0; i4 < P1_EPT / 4; ++i4) {
        int eid0 = cb + (i4 * 256 + t) * 4;
        int4 s4, d4;
        bool full = (eid0 + 3 < e);
        if (full) {
            s4 = *(const int4*)(src + eid0);
            d4 = *(const int4*)(dst + eid0);
        }
#pragma unroll
        for (int j = 0; j < 4; ++j) {
            int i = i4 * 4 + j;
            int eid = eid0 + j;
            if (full) {
                sr[i] = (&s4.x)[j];
                ds[i] = (&d4.x)[j];
            } else if (eid < e) {
                sr[i] = src[eid];
                ds[i] = dst[eid];
            }
            rk[i] = (eid < e) ? atomicAdd(&cnt[wv][ds[i] >> BKT_SHIFT], 1) : -1;
        }
    }
    __syncthreads();
    for (int b = t; b < nbkt; b += 256) {
        int c0 = cnt[0][b], c1 = cnt[1][b], c2 = cnt[2][b], c3 = cnt[3][b];
        int tot = c0 + c1 + c2 + c3;
        if (tot > 0) {
            int gb = atomicAdd(&gcur[b], tot);
            base_l[0][b] = gb;
            base_l[1][b] = gb + c0;
            base_l[2][b] = gb + c0 + c1;
            base_l[3][b] = gb + c0 + c1 + c2;
        }
    }
    __syncthreads();
#pragma unroll
    for (int i = 0; i < P1_EPT; ++i) {
        if (rk[i] >= 0) {
            int b = ds[i] >> BKT_SHIFT;
            part[base_l[wv][b] + rk[i]] = (sr[i] << BKT_SHIFT) | (ds[i] & (BKT_SIZE - 1));
        }
    }
}

// 1 block x 256: bucket counts from cursors, exclusive scan -> bbase[0..nbkt].
__global__ void cnt_scan(const int* __restrict__ gcur, int* __restrict__ bbase,
                         int nbkt, int e_total) {
    __shared__ int tmp[256];
    int t = threadIdx.x;
    int b0 = 2 * t, b1 = 2 * t + 1;
    int c0 = (b0 < nbkt) ? (gcur[b0] - b0 * BKT_CAP) : 0;
    int c1 = (b1 < nbkt) ? (gcur[b1] - b1 * BKT_CAP) : 0;
    int s = c0 + c1;
    tmp[t] = s;
    __syncthreads();
    for (int o = 1; o < 256; o <<= 1) {
        int x = tmp[t];
        int y = (t >= o) ? tmp[t - o] : 0;
        __syncthreads();
        tmp[t] = x + y;
        __syncthreads();
    }
    int excl = tmp[t] - s;
    if (b0 < nbkt) bbase[b0] = excl;
    if (b1 < nbkt) bbase[b1] = excl + c0;
    if (t == 0) bbase[nbkt] = e_total;
}

// Per bucket (256 dst nodes): per-dst counts in LDS, 256-scan, write row_off
// slice (coalesced) + scatter into the bucket's L2-resident csr window.
__global__ __launch_bounds__(256) void finesort2(
        const int* __restrict__ part, const int* __restrict__ gcur,
        const int* __restrict__ bbase, int* __restrict__ row_off,
        int* __restrict__ csr_src, int n, int e_total, int nbkt) {
    __shared__ int cnt[BKT_SIZE];
    __shared__ int cur[BKT_SIZE];
    __shared__ int tmp[BKT_SIZE];
    int b = blockIdx.x, t = threadIdx.x;
    int d0 = b << BKT_SHIFT;
    int nloc = min(BKT_SIZE, n - d0);
    cnt[t] = 0;
    __syncthreads();
    int abase = b * BKT_CAP, aend = gcur[b];
    for (int i = abase + t; i < aend; i += 256)
        atomicAdd(&cnt[part[i] & (BKT_SIZE - 1)], 1);
    __syncthreads();
    int c = cnt[t];
    tmp[t] = c;
    __syncthreads();
    for (int o = 1; o < 256; o <<= 1) {
        int x = tmp[t];
        int y = (t >= o) ? tmp[t - o] : 0;
        __syncthreads();
        tmp[t] = x + y;
        __syncthreads();
    }
    int pos0 = bbase[b] + tmp[t] - c;
    cur[t] = pos0;
    if (t < nloc) row_off[d0 + t] = pos0;
    if (b == nbkt - 1 && t == 0) row_off[n] = e_total;
    __syncthreads();
    for (int i = abase + t; i < aend; i += 256) {
        int pk = part[i];
        int pos = atomicAdd(&cur[pk & (BKT_SIZE - 1)], 1);
        csr_src[pos] = ((unsigned)pk) >> BKT_SHIFT;
    }
}

// ---------------- W decomposition into MFMA frag order ----------------
__global__ void wprep_kernel(const float* __restrict__ W, unsigned short* __restrict__ wh,
                             unsigned short* __restrict__ wl, int K) {
    int idx = blockIdx.x * blockDim.x + threadIdx.x;   // (kt*4+fb)*64 + lane
    int KT = K / 32;
    if (idx >= KT * 4 * 64) return;
    int lane = idx & 63;
    int fbkt = idx >> 6;
    int fb = fbkt & 3, kt = fbkt >> 2;
    int q = lane >> 4, c = lane & 15;
    for (int j = 0; j < 8; ++j) {
        float w = W[(kt * 32 + q * 8 + j) * 64 + fb * 16 + c];
        unsigned short hi = f2bf(w);
        wh[idx * 8 + j] = hi;
        wl[idx * 8 + j] = f2bf(w - bf2f(hi));
    }
}

// ---------------- MFMA GEMM + attention dots ----------------
// h[N,64] = x[N,K] @ W[K,64] via v_mfma_f32_16x16x32_bf16, bf16x3 split.
// IN = float (layer1) or __half (layer2; fp16 splits into bf16 hi+lo exactly).
template <int KT, typename IN>
__global__ __launch_bounds__(256) void gemm_mfma_kernel(
        const IN* __restrict__ x, const unsigned short* __restrict__ wh,
        const unsigned short* __restrict__ wl,
        const float* __restrict__ al, const float* __restrict__ ar,
        __half* __restrict__ h16, float* __restrict__ el,
        float* __restrict__ er, int n) {
    constexpr int K = KT * 32;
    constexpr int WFRAG = KT * 4 * 64 * 8;   // shorts
    __shared__ unsigned short Wh[WFRAG];
    __shared__ unsigned short Wl[WFRAG];
    for (int i = threadIdx.x; i < WFRAG / 8; i += 256) {
        ((float4*)Wh)[i] = ((const float4*)wh)[i];
        ((float4*)Wl)[i] = ((const float4*)wl)[i];
    }
    __syncthreads();

    int lane = threadIdx.x & 63;
    int q = lane >> 4, c = lane & 15;
    int wave = (int)((blockIdx.x * blockDim.x + threadIdx.x) >> 6);
    int nwaves = (gridDim.x * blockDim.x) >> 6;
    int ntiles = (n + 15) >> 4;

    float alv[4], arv[4];
#pragma unroll
    for (int fb = 0; fb < 4; ++fb) {
        alv[fb] = al[fb * 16 + c];
        arv[fb] = ar[fb * 16 + c];
    }

    for (int t = wave; t < ntiles; t += nwaves) {
        int v0 = t * 16;
        int row = min(v0 + c, n - 1);
        const IN* xr = x + (size_t)row * K + q * 8;

        short8 Ah[KT], Al[KT];
#pragma unroll
        for (int kt = 0; kt < KT; ++kt) {
            float xv[8];
            if constexpr (std::is_same<IN, float>::value) {
                *(float4*)&xv[0] = *(const float4*)(xr + kt * 32);
                *(float4*)&xv[4] = *(const float4*)(xr + kt * 32 + 4);
            } else {
                __half hh[8];
                *(uint4*)hh = *(const uint4*)(xr + kt * 32);
#pragma unroll
                for (int j = 0; j < 8; ++j) xv[j] = __half2float(hh[j]);
            }
#pragma unroll
            for (int j = 0; j < 8; ++j) {
                unsigned short hi = f2bf(xv[j]);
                Ah[kt][j] = (short)hi;
                Al[kt][j] = (short)f2bf(xv[j] - bf2f(hi));
            }
        }

        float4v acc[4];
#pragma unroll
        for (int fb = 0; fb < 4; ++fb) acc[fb] = (float4v)0.f;

#pragma unroll
        for (int kt = 0; kt < KT; ++kt) {
#pragma unroll
            for (int fb = 0; fb < 4; ++fb) {
                short8 bh = *(const short8*)&Wh[((kt * 4 + fb) * 64 + lane) * 8];
                short8 bl = *(const short8*)&Wl[((kt * 4 + fb) * 64 + lane) * 8];
                acc[fb] = __builtin_amdgcn_mfma_f32_16x16x32_bf16(Ah[kt], bh, acc[fb], 0, 0, 0);
                acc[fb] = __builtin_amdgcn_mfma_f32_16x16x32_bf16(Al[kt], bh, acc[fb], 0, 0, 0);
                acc[fb] = __builtin_amdgcn_mfma_f32_16x16x32_bf16(Ah[kt], bl, acc[fb], 0, 0, 0);
            }
        }

#pragma unroll
        for (int r = 0; r < 4; ++r) {
            int v = v0 + q * 4 + r;
            float pl = 0.f, pr = 0.f;
            bool ok = (v < n);
#pragma unroll
            for (int fb = 0; fb < 4; ++fb) {
                float hv = acc[fb][r];
                if (ok) h16[(size_t)v * 64 + fb * 16 + c] = __float2half(hv);
                pl = fmaf(hv, alv[fb], pl);
                pr = fmaf(hv, arv[fb], pr);
            }
#pragma unroll
            for (int off = 8; off > 0; off >>= 1) {
                pl += __shfl_xor(pl, off);
                pr += __shfl_xor(pr, off);
            }
            if (ok && c == 0) { el[v] = pl; er[v] = pr; }
        }
    }
}

// ---------------- softmax-aggregate ----------------
// 4 edges per wave step (16-lane groups, uint2 = 4 fp16 features per lane).
// OUT = __half (layer1: relu'd hr) or float (layer2: d_out).
template <typename OUT>
__global__ __launch_bounds__(256) void agg_kernel(
        const int* __restrict__ row_off, const int* __restrict__ csr_src,
        const __half* __restrict__ h16, const float* __restrict__ el,
        const float* __restrict__ er, const float* __restrict__ bias,
        OUT* __restrict__ out, int n, int do_relu) {
    int lane = threadIdx.x & 63;
    int grp = lane >> 4;      // 0..3: edge slot within a 4-edge step
    int c = lane & 15;        // feature quad: features 4c..4c+3
    int gwave = rfl_i((int)((blockIdx.x * blockDim.x + threadIdx.x) >> 6));
    int nwaves = (gridDim.x * blockDim.x) >> 6;
    float4 b4 = ((const float4*)bias)[c];
    for (int v = gwave; v < n; v += nwaves) {
        int rs = rfl_i(row_off[v]), re = rfl_i(row_off[v + 1]);
        float er_v = er[v];
        float a0 = 0.f, a1 = 0.f, a2 = 0.f, a3 = 0.f, ssum = 0.f;
        for (int base = rs; base < re; base += 64) {
            int cnt = min(64, re - base);
            int s_e = 0;
            float ex = 0.f;
            if (lane < cnt) {
                s_e = csr_src[base + lane];
                float ev = el[s_e] + er_v;
                ev = (ev >= 0.f) ? ev : NEG_SLOPE * ev;
                ex = __expf(ev);
            }
            float cs = ex;
#pragma unroll
            for (int off = 32; off > 0; off >>= 1) cs += __shfl_xor(cs, off);
            ssum += cs;
            int cnt16 = (cnt + 15) & ~15;
            for (int j = 0; j < cnt16; j += 16) {
                int sj[4];
                float exj[4];
                uint2 hv[4];
#pragma unroll
                for (int u = 0; u < 4; ++u) {
                    int idx = j + 4 * u + grp;
                    sj[u] = __shfl(s_e, idx);
                    exj[u] = __shfl(ex, idx);
                    hv[u] = *((const uint2*)(h16 + (size_t)sj[u] * 64) + c);
                }
#pragma unroll
                for (int u = 0; u < 4; ++u) {
                    float2 f01 = __half22float2(*(__half2*)&hv[u].x);
                    float2 f23 = __half22float2(*(__half2*)&hv[u].y);
                    a0 = fmaf(exj[u], f01.x, a0);
                    a1 = fmaf(exj[u], f01.y, a1);
                    a2 = fmaf(exj[u], f23.x, a2);
                    a3 = fmaf(exj[u], f23.y, a3);
                }
            }
        }
        // combine the 4 edge-groups: reduce over lane bits 4,5
#pragma unroll
        for (int off = 16; off < 64; off <<= 1) {
            a0 += __shfl_xor(a0, off);
            a1 += __shfl_xor(a1, off);
            a2 += __shfl_xor(a2, off);
            a3 += __shfl_xor(a3, off);
        }
        if (lane < 16) {
            float4 o;
            if (re > rs) {
                float inv = 1.0f / ssum;
                o.x = fmaf(a0, inv, b4.x);
                o.y = fmaf(a1, inv, b4.y);
                o.z = fmaf(a2, inv, b4.z);
                o.w = fmaf(a3, inv, b4.w);
            } else {
                o = b4;
            }
            if (do_relu) {
                o.x = fmaxf(o.x, 0.f);
                o.y = fmaxf(o.y, 0.f);
                o.z = fmaxf(o.z, 0.f);
                o.w = fmaxf(o.w, 0.f);
            }
            if constexpr (std::is_same<OUT, __half>::value) {
                uint2 pk;
                *(__half2*)&pk.x = __float22half2_rn(make_float2(o.x, o.y));
                *(__half2*)&pk.y = __float22half2_rn(make_float2(o.z, o.w));
                ((uint2*)(out + (size_t)v * 64))[c] = pk;
            } else {
                ((float4*)(out + (size_t)v * 64))[c] = o;
            }
        }
    }
}

extern "C" void kernel_launch(void* const* d_in, const int* in_sizes, int n_in,
                              void* d_out, int out_size, void* d_ws, size_t ws_size,
                              hipStream_t stream) {
    (void)n_in; (void)out_size; (void)ws_size;
    const float* features = (const float*)d_in[0];
    // d_in[1] = edge_weights, unused by the reference forward
    const int*   src = (const int*)d_in[2];
    const int*   dst = (const int*)d_in[3];
    const float* W1  = (const float*)d_in[4];
    const float* al1 = (const float*)d_in[5];
    const float* ar1 = (const float*)d_in[6];
    const float* b1  = (const float*)d_in[7];
    const float* W2  = (const float*)d_in[8];
    const float* al2 = (const float*)d_in[9];
    const float* ar2 = (const float*)d_in[10];
    const float* b2  = (const float*)d_in[11];

    const int n = in_sizes[0] / 128;   // 100000
    const int e = in_sizes[2];         // 1600000
    float* out = (float*)d_out;

    char* p = (char*)d_ws;
    auto alloc = [&](size_t bytes) -> char* {
        char* q = p;
        p += (bytes + 255) & ~(size_t)255;
        return q;
    };
    int*    row_off = (int*)alloc((size_t)(n + 1) * 4);
    int*    csr_src = (int*)alloc((size_t)e * 4);
    __half* h16     = (__half*)alloc((size_t)n * 64 * 2);
    __half* hr      = (__half*)alloc((size_t)n * 64 * 2);
    float*  el      = (float*)alloc((size_t)n * 4);
    float*  er      = (float*)alloc((size_t)n * 4);
    int*    gcur    = (int*)alloc(512 * 4);
    int*    bbase   = (int*)alloc(513 * 4);
    unsigned short* w1h = (unsigned short*)alloc(4 * 4 * 64 * 8 * 2);
    unsigned short* w1l = (unsigned short*)alloc(4 * 4 * 64 * 8 * 2);
    unsigned short* w2h = (unsigned short*)alloc(2 * 4 * 64 * 8 * 2);
    unsigned short* w2l = (unsigned short*)alloc(2 * 4 * 64 * 8 * 2);
    // arena (nbkt*CAP ints = 19.2MB) aliases h16+hr (25.6MB contiguous):
    // consumed by finesort2 before gemm1/agg1 write h16/hr.
    int*    part    = (int*)h16;

    const int nbkt = (n + BKT_SIZE - 1) >> BKT_SHIFT;   // 391

    // W decomposition (tiny, once per launch)
    wprep_kernel<<<4, 256, 0, stream>>>(W1, w1h, w1l, 128);
    wprep_kernel<<<2, 256, 0, stream>>>(W2, w2h, w2l, 64);

    // CSR by dst (shared by both layers)
    init_cur<<<2, 256, 0, stream>>>(gcur, nbkt);
    partition_kernel<<<(e + 256 * P1_EPT - 1) / (256 * P1_EPT), 256, 0, stream>>>(
        src, dst, e, gcur, part, nbkt);
    cnt_scan<<<1, 256, 0, stream>>>(gcur, bbase, nbkt, e);
    finesort2<<<nbkt, 256, 0, stream>>>(part, gcur, bbase, row_off, csr_src, n, e, nbkt);

    // layer 1
    gemm_mfma_kernel<4, float><<<512, 256, 0, stream>>>(features, w1h, w1l, al1, ar1,
                                                        h16, el, er, n);
    agg_kernel<__half><<<4096, 256, 0, stream>>>(row_off, csr_src, h16, el, er, b1, hr, n, 1);

    // layer 2
    gemm_mfma_kernel<2, __half><<<512, 256, 0, stream>>>(hr, w2h, w2l, al2, ar2,
                                                         h16, el, er, n);
    agg_kernel<float><<<4096, 256, 0, stream>>>(row_off, csr_src, h16, el, er, b2, out, n, 0);
}